// Round 18
// baseline (262.613 us; speedup 1.0000x reference)
//
#include <hip/hip_runtime.h>
#include <hip/hip_fp16.h>
#include <hip/hip_bf16.h>
#include <math.h>

typedef unsigned short u16;
typedef __attribute__((ext_vector_type(8))) short bf16x8;
typedef __attribute__((ext_vector_type(8))) unsigned short u16x8;
typedef __attribute__((ext_vector_type(4))) unsigned short u16x4;
typedef __attribute__((ext_vector_type(4))) float f32x4;

static constexpr float CLAMPF = 3.8918202981106265f; // -log(1/0.98 - 1)
static constexpr float SCALEF = 0.125f;              // 1/sqrt(64)
static constexpr float ASCALE = 16384.f;             // 2^14 alpha storage scale

__device__ __forceinline__ u16 f2bf(float x) {
    __hip_bfloat16 h = __float2bfloat16(x);
    return *reinterpret_cast<u16*>(&h);
}

// DPP row_shr:1 (0x111): lane L <- lane L-1 within each 16-lane row;
// bound_ctrl zero-fills lanes 0/16/32/48. VALID on CDNA (row_bcast15 is NOT —
// removed on gfx90a+). Row-boundary lanes patched via v_readlane.
// Must be called in uniform control flow.
__device__ __forceinline__ float dpp_shr1(float x) {
    int r = __builtin_amdgcn_update_dpp(0, __float_as_int(x), 0x111, 0xF, 0xF, true);
    return __int_as_float(r);
}

// ---------------------------------------------------------------------------
// Fused f32 -> bf16 conversion for all 5 inputs (one dispatch).
// ---------------------------------------------------------------------------
__global__ __launch_bounds__(256)
void cvt_all_k(const float* __restrict__ q, const float* __restrict__ key,
               const float* __restrict__ val, const float* __restrict__ W,
               const float* __restrict__ ow,
               u16* __restrict__ QBF, u16* __restrict__ KBF,
               u16* __restrict__ VBF, u16* __restrict__ WBF,
               u16* __restrict__ OWBF)
{
    long i = (long)blockIdx.x * 256 + threadIdx.x;
    const float* src; u16* dst; long off;
    if (i < 524288)       { src = q;   dst = QBF;  off = i; }
    else if (i < 1572864) { src = key; dst = KBF;  off = i - 524288; }
    else if (i < 2621440) { src = val; dst = VBF;  off = i - 1572864; }
    else if (i < 3670016) { src = W;   dst = WBF;  off = i - 2621440; }
    else if (i < 3932160) { src = ow;  dst = OWBF; off = i - 3670016; }
    else return;
    float4 v = ((const float4*)src)[off];
    u16x4 o; o.x = f2bf(v.x); o.y = f2bf(v.y); o.z = f2bf(v.z); o.w = f2bf(v.w);
    ((u16x4*)dst)[off] = o;
}

// ---------------------------------------------------------------------------
// bf16 MFMA GEMM, NT form: C[m][n] = sum_k A[m][k]*B[n][k]  (+ epilogue)
// EPI: 0=bf16(+opt bias), 1=fp16 sigmoid(CLAMP*tanh(x)), 3=f32+bias,
//      4=bf16 V-transpose store VT[((b*16+h)*64+d)*512 + k] + bias
// TRI: phi triangular skip — tiles with k-tile > q-tile are zero-filled.
// ---------------------------------------------------------------------------
template<int TM, int TN, int EPI, bool TRI = false>
__global__ __launch_bounds__(256)
void mfma_nt(const u16* __restrict__ Ag, const u16* __restrict__ Bg,
             void* __restrict__ Cg, const float* __restrict__ bias,
             int K, int lda, int ldb, int ldc,
             long sAb, long sAh, long sBb, long sBh, long sCb, long sCh,
             int hdiv)
{
    __shared__ u16 As[TM * 64];
    __shared__ u16 Bs[TN * 64];

    int z = blockIdx.z;
    int b = z / hdiv, h = z % hdiv;
    const u16* A = Ag + (long)b * sAb + (long)h * sAh;
    const u16* B = Bg + (long)b * sBb + (long)h * sBh;

    int tid = threadIdx.x;
    int bm = blockIdx.y * TM, bn = blockIdx.x * TN;

    constexpr int AC = TM / 32;
    constexpr int BC = TN / 32;
    int srow = tid >> 3;          // 0..31
    int scol = (tid & 7) * 8;     // 0..56

    int wid = tid >> 6, lane = tid & 63;
    int wr = wid >> 1, wc = wid & 1;
    constexpr int MI = TM / 32;
    constexpr int NI = TN / 32;
    int arow0 = wr * (TM / 2) + (lane & 15);
    int bcol0 = wc * (TN / 2) + (lane & 15);
    int koff = (lane >> 4) * 8;

    if constexpr (TRI) {
        if (blockIdx.x > blockIdx.y) {   // strictly upper triangle: zero-fill
            __half* C = (__half*)Cg + (long)b * sCb + (long)h * sCh;
            int rb = bm + wr * (TM / 2) + (lane >> 4) * 4;
            int cb = bn + wc * (TN / 2) + (lane & 15);
            __half z16 = __float2half(0.f);
#pragma unroll
            for (int mi = 0; mi < MI; ++mi)
#pragma unroll
                for (int ni = 0; ni < NI; ++ni)
#pragma unroll
                    for (int r = 0; r < 4; ++r)
                        C[(long)(rb + 16 * mi + r) * ldc + cb + 16 * ni] = z16;
            return;
        }
    }

    f32x4 acc[MI][NI];
#pragma unroll
    for (int i = 0; i < MI; ++i)
#pragma unroll
        for (int j = 0; j < NI; ++j) acc[i][j] = (f32x4){0.f, 0.f, 0.f, 0.f};

    for (int kt = 0; kt < K; kt += 64) {
        u16x8 av[AC], bv[BC];
#pragma unroll
        for (int c = 0; c < AC; ++c)
            av[c] = *(const u16x8*)(A + (long)(bm + srow + 32 * c) * lda + kt + scol);
#pragma unroll
        for (int c = 0; c < BC; ++c)
            bv[c] = *(const u16x8*)(B + (long)(bn + srow + 32 * c) * ldb + kt + scol);
        __syncthreads();
#pragma unroll
        for (int c = 0; c < AC; ++c)
            *(u16x8*)&As[(srow + 32 * c) * 64 + scol] = av[c];
#pragma unroll
        for (int c = 0; c < BC; ++c)
            *(u16x8*)&Bs[(srow + 32 * c) * 64 + scol] = bv[c];
        __syncthreads();

#pragma unroll
        for (int ks = 0; ks < 2; ++ks) {
            bf16x8 af[MI], bfr[NI];
#pragma unroll
            for (int mi = 0; mi < MI; ++mi)
                af[mi] = *(const bf16x8*)&As[(arow0 + 16 * mi) * 64 + ks * 32 + koff];
#pragma unroll
            for (int ni = 0; ni < NI; ++ni)
                bfr[ni] = *(const bf16x8*)&Bs[(bcol0 + 16 * ni) * 64 + ks * 32 + koff];
#pragma unroll
            for (int mi = 0; mi < MI; ++mi)
#pragma unroll
                for (int ni = 0; ni < NI; ++ni)
                    acc[mi][ni] = __builtin_amdgcn_mfma_f32_16x16x32_bf16(
                        af[mi], bfr[ni], acc[mi][ni], 0, 0, 0);
        }
    }

    // Epilogue
    int rbase = bm + wr * (TM / 2) + (lane >> 4) * 4;
    int cbase = bn + wc * (TN / 2) + (lane & 15);
#pragma unroll
    for (int mi = 0; mi < MI; ++mi) {
#pragma unroll
        for (int ni = 0; ni < NI; ++ni) {
            int m0 = rbase + 16 * mi;
            int n = cbase + 16 * ni;
            if constexpr (EPI == 0) {
                u16* C = (u16*)Cg + (long)b * sCb + (long)h * sCh;
                float bvv = bias ? bias[n] : 0.f;
#pragma unroll
                for (int r = 0; r < 4; ++r)
                    C[(long)(m0 + r) * ldc + n] = f2bf(acc[mi][ni][r] + bvv);
            } else if constexpr (EPI == 1) {
                __half* C = (__half*)Cg + (long)b * sCb + (long)h * sCh;
#pragma unroll
                for (int r = 0; r < 4; ++r) {
                    float x = acc[mi][ni][r];
                    float e2 = __expf(2.f * x);
                    float tv = CLAMPF - (2.f * CLAMPF) * __builtin_amdgcn_rcpf(e2 + 1.f);
                    float pv = __builtin_amdgcn_rcpf(1.f + __expf(-tv));
                    C[(long)(m0 + r) * ldc + n] = __float2half(pv);
                }
            } else if constexpr (EPI == 3) {
                float* C = (float*)Cg + (long)b * sCb + (long)h * sCh;
                float bvv = bias[n];
#pragma unroll
                for (int r = 0; r < 4; ++r)
                    C[(long)(m0 + r) * ldc + n] = acc[mi][ni][r] + bvv;
            } else { // EPI == 4: VT[((b*16 + n/64)*64 + n%64)*512 + k], k = m0+r
                u16* C = (u16*)Cg;
                float bvv = bias[n];
                long vaddr = ((long)(b * 16 + (n >> 6)) * 64 + (n & 63)) * 512 + m0;
                u16x4 pk;
                pk.x = f2bf(acc[mi][ni][0] + bvv);
                pk.y = f2bf(acc[mi][ni][1] + bvv);
                pk.z = f2bf(acc[mi][ni][2] + bvv);
                pk.w = f2bf(acc[mi][ni][3] + bvv);
                *(u16x4*)(C + vaddr) = pk;
            }
        }
    }
}

// ---------------------------------------------------------------------------
// Monotonic DP, LINEAR probability domain (scaled 2^14, mass-conserving).
// TRIANGULAR 512x512. TWO independent slices per WAVE (ILP): slice A and
// slice B's dependency chains interleave in one wave's issue stream —
// fills the per-column cadence stalls that r12-r17 showed are insensitive
// to prefetch depth / shuffle flavor / store placement, without r17's
// 8x per-CU memory concentration (only 2 slices -> 2 MB per CU).
// 32 blocks x 64 thr; lane owns 8 contiguous k-rows of each slice.
// Shift: DPP row_shr:1 + v_readlane(15/31/47) patches. Depth-4 prefetch
// per slice (8 loads in flight total, same as r15).
// ---------------------------------------------------------------------------
#define DPLX(PP, J) (*(const uint4*)((PP) + (long)min((J), 510) * 512 + k0))

#define DSTEPX(PC, J, A_, AL_) do { \
    const __half2* hp = (const __half2*)&(PC); \
    float pv[8]; \
    { float2 q01 = __half22float2(hp[0]); pv[0] = q01.x; pv[1] = q01.y; } \
    { float2 q23 = __half22float2(hp[1]); pv[2] = q23.x; pv[3] = q23.y; } \
    { float2 q45 = __half22float2(hp[2]); pv[4] = q45.x; pv[5] = q45.y; } \
    { float2 q67 = __half22float2(hp[3]); pv[6] = q67.x; pv[7] = q67.y; } \
    float c[8]; \
    _Pragma("unroll") \
    for (int r = 0; r < 8; ++r) c[r] = fmaf(-A_[r], pv[r], A_[r]); \
    float _s1 = dpp_shr1(c[7]);                 /* full-wave, uniform flow */ \
    int _c7i = __float_as_int(c[7]); \
    float _r15 = __int_as_float(__builtin_amdgcn_readlane(_c7i, 15)); \
    float _r31 = __int_as_float(__builtin_amdgcn_readlane(_c7i, 31)); \
    float _r47 = __int_as_float(__builtin_amdgcn_readlane(_c7i, 47)); \
    float cp = _s1; \
    cp = l16 ? _r15 : cp; \
    cp = l32 ? _r31 : cp; \
    cp = l48 ? _r47 : cp; \
    A_[0] = fmaf(A_[0], pv[0], cp); \
    _Pragma("unroll") \
    for (int r = 1; r < 8; ++r) A_[r] = fmaf(A_[r], pv[r], c[r - 1]); \
    uint4 st; \
    { __half2 h0 = __floats2half2_rn(A_[0], A_[1]), h1 = __floats2half2_rn(A_[2], A_[3]); \
      st.x = *(unsigned*)&h0; st.y = *(unsigned*)&h1; } \
    { __half2 h2 = __floats2half2_rn(A_[4], A_[5]), h3 = __floats2half2_rn(A_[6], A_[7]); \
      st.z = *(unsigned*)&h2; st.w = *(unsigned*)&h3; } \
    *(uint4*)((AL_) + (long)(J) * 512 + k0) = st; \
} while (0)

__global__ __launch_bounds__(64)
void mono_dp_k(const __half* __restrict__ P, __half* __restrict__ AL)
{
    int nA = blockIdx.x * 2, nB = nA + 1;
    int lane = threadIdx.x;                 // 0..63
    const __half* pA = P + (long)nA * 262144;
    const __half* pB = P + (long)nB * 262144;
    __half* alA = AL + (long)nA * 262144;
    __half* alB = AL + (long)nB * 262144;
    int k0 = lane * 8;
    const bool l16 = (lane == 16), l32 = (lane == 32), l48 = (lane == 48);

    float aA[8], aB[8];
#pragma unroll
    for (int r = 0; r < 8; ++r) { aA[r] = 0.f; aB[r] = 0.f; }
    if (lane == 0) { aA[0] = ASCALE; aB[0] = ASCALE; }
    {   // column 0 = init distribution (both slices)
        uint4 st;
        __half2 h0 = __floats2half2_rn(aA[0], aA[1]), h1 = __floats2half2_rn(aA[2], aA[3]);
        __half2 h2 = __floats2half2_rn(aA[4], aA[5]), h3 = __floats2half2_rn(aA[6], aA[7]);
        st.x = *(unsigned*)&h0; st.y = *(unsigned*)&h1;
        st.z = *(unsigned*)&h2; st.w = *(unsigned*)&h3;
        *(uint4*)(alA + k0) = st;
        *(uint4*)(alB + k0) = st;
    }

    // iteration j consumes p column j-1 (cols 0..510); depth-4/slice prefetch
    int j = 1;
    uint4 fA0 = DPLX(pA, 0), fA1 = DPLX(pA, 1), fA2 = DPLX(pA, 2), fA3 = DPLX(pA, 3);
    uint4 fB0 = DPLX(pB, 0), fB1 = DPLX(pB, 1), fB2 = DPLX(pB, 2), fB3 = DPLX(pB, 3);

    while (j + 3 < 512) {
        DSTEPX(fA0, j, aA, alA); DSTEPX(fB0, j, aB, alB);
        fA0 = DPLX(pA, j + 3); fB0 = DPLX(pB, j + 3); ++j;
        DSTEPX(fA1, j, aA, alA); DSTEPX(fB1, j, aB, alB);
        fA1 = DPLX(pA, j + 3); fB1 = DPLX(pB, j + 3); ++j;
        DSTEPX(fA2, j, aA, alA); DSTEPX(fB2, j, aB, alB);
        fA2 = DPLX(pA, j + 3); fB2 = DPLX(pB, j + 3); ++j;
        DSTEPX(fA3, j, aA, alA); DSTEPX(fB3, j, aB, alB);
        fA3 = DPLX(pA, j + 3); fB3 = DPLX(pB, j + 3); ++j;
    }
    while (j < 512) {
        DSTEPX(fA0, j, aA, alA); DSTEPX(fB0, j, aB, alB);
        fA0 = fA1; fA1 = fA2; fA2 = fA3;
        fB0 = fB1; fB1 = fB2; fB2 = fB3;
        ++j;
    }
}

// ---------------------------------------------------------------------------
// Fused attention, k < 512 only (alpha == 0 beyond), 4-way k-split of 128.
// grid (64 n, 32 q-groups); block = 4 waves; wave w handles 16 q x 128 k.
// Single k-tile per wave -> no online rescale. Wave skipped entirely if its
// k-range > qg+15 (alpha all zero there). Partials combined in LDS.
// ---------------------------------------------------------------------------
__global__ __launch_bounds__(256, 4)
void fused_attn_k(const u16* __restrict__ XQAQ, const u16* __restrict__ XK,
                  const u16* __restrict__ VT, const __half* __restrict__ AL,
                  u16* __restrict__ XO)
{
    __shared__ u16 wtile[4][2048];     // per-wave 16q x 128k bf16 (swizzled)
    __shared__ float co[4][16][64];    // per-wave partial O (q, d)
    __shared__ float cml[4][2][16];    // per-wave m, l per q

    int n = blockIdx.x; int b = n >> 4, h = n & 15;
    int tid = threadIdx.x, wave = tid >> 6, lane = tid & 63;
    int l15 = lane & 15, l4 = lane >> 4;
    int qg = blockIdx.y * 16;          // q base within 512
    u16* wlds = wtile[wave];
    int swz = (l15 & 7) << 3;

    float m = -3.0e38f, lsum = 0.f;
    f32x4 o[4];
#pragma unroll
    for (int df = 0; df < 4; ++df) o[df] = (f32x4){0.f, 0.f, 0.f, 0.f};

    if (wave * 128 < qg + 16) {        // triangular: this wave's k-range has mass
        // Q B-frags (col=q=l15)
        const u16* qbase = XQAQ + (long)(b * 512 + qg + l15) * 2048 + 1024 + h * 64 + l4 * 8;
        bf16x8 qf0 = *(const bf16x8*)(qbase);
        bf16x8 qf1 = *(const bf16x8*)(qbase + 32);

        const u16* kbase = XK + (long)(b * 512 + wave * 128 + l15) * 1024 + h * 64 + l4 * 8;
        const __half* abase = AL + (long)(n * 512 + qg + l15) * 512 + wave * 128 + l4 * 4;
        const u16* vbase = VT + (long)(n * 64 + l15) * 512 + wave * 128 + l4 * 8;

        // alpha regs (q=l15, k = wave*128 + kf*16 + l4*4 + r)
        uint2 areg[8];
#pragma unroll
        for (int kf = 0; kf < 8; ++kf)
            areg[kf] = *(const uint2*)(abase + kf * 16);

        // scores: s[kf][r] for q=l15, k = wave*128 + kf*16 + l4*4 + r
        f32x4 s[8];
#pragma unroll
        for (int kf = 0; kf < 8; ++kf) {
            const u16* kb = kbase + (long)(kf * 16) * 1024;
            bf16x8 k0 = *(const bf16x8*)kb;
            bf16x8 k1 = *(const bf16x8*)(kb + 32);
            f32x4 acc = (f32x4){0.f, 0.f, 0.f, 0.f};
            acc = __builtin_amdgcn_mfma_f32_16x16x32_bf16(k0, qf0, acc, 0, 0, 0);
            acc = __builtin_amdgcn_mfma_f32_16x16x32_bf16(k1, qf1, acc, 0, 0, 0);
            s[kf] = acc;
        }

        // tile max per q (in-lane, then across l4 groups)
        float mt = -3.0e38f;
#pragma unroll
        for (int kf = 0; kf < 8; ++kf)
            mt = fmaxf(mt, fmaxf(fmaxf(s[kf][0], s[kf][1]), fmaxf(s[kf][2], s[kf][3])));
        mt = fmaxf(mt, __shfl_xor(mt, 16, 64));
        mt = fmaxf(mt, __shfl_xor(mt, 32, 64));
        m = mt;
        float negm = -mt * SCALEF;

        // w = alpha * exp(SCALE*(s - m)), accumulate l, store swizzled LDS
#pragma unroll
        for (int kf = 0; kf < 8; ++kf) {
            float2 a01 = __half22float2(*(__half2*)&areg[kf].x);
            float2 a23 = __half22float2(*(__half2*)&areg[kf].y);
            float w0 = a01.x * __expf(fmaf(s[kf][0], SCALEF, negm));
            float w1 = a01.y * __expf(fmaf(s[kf][1], SCALEF, negm));
            float w2 = a23.x * __expf(fmaf(s[kf][2], SCALEF, negm));
            float w3 = a23.y * __expf(fmaf(s[kf][3], SCALEF, negm));
            lsum += (w0 + w1) + (w2 + w3);
            u16x4 wp; wp.x = f2bf(w0); wp.y = f2bf(w1); wp.z = f2bf(w2); wp.w = f2bf(w3);
            *(u16x4*)&wlds[(l15 * 128 + kf * 16 + l4 * 4) ^ swz] = wp;
        }

        // PV over this 128-k tile
#pragma unroll
        for (int ks2 = 0; ks2 < 4; ++ks2) {
            bf16x8 wf = *(const bf16x8*)&wlds[(l15 * 128 + ks2 * 32 + l4 * 8) ^ swz];
#pragma unroll
            for (int df = 0; df < 4; ++df) {
                const u16* vb = vbase + (long)(df * 16) * 512 + ks2 * 32;
                bf16x8 vf = *(const bf16x8*)vb;
                o[df] = __builtin_amdgcn_mfma_f32_16x16x32_bf16(wf, vf, o[df], 0, 0, 0);
            }
        }

        // full-row l per q
        lsum += __shfl_xor(lsum, 16, 64);
        lsum += __shfl_xor(lsum, 32, 64);
    }

    if (lane < 16) { cml[wave][0][l15] = m; cml[wave][1][l15] = lsum; }
#pragma unroll
    for (int df = 0; df < 4; ++df)
#pragma unroll
        for (int r = 0; r < 4; ++r)
            co[wave][l4 * 4 + r][df * 16 + l15] = o[df][r];
    __syncthreads();

    // combine 4 k-split partials; thread handles (q = tid>>4, d0 = (tid&15)*4)
    int q = tid >> 4, d0 = (tid & 15) * 4;
    float m0 = cml[0][0][q], m1 = cml[1][0][q], m2 = cml[2][0][q], m3 = cml[3][0][q];
    float ms = fmaxf(fmaxf(m0, m1), fmaxf(m2, m3));
    float c0w = __expf((m0 - ms) * SCALEF), c1w = __expf((m1 - ms) * SCALEF);
    float c2w = __expf((m2 - ms) * SCALEF), c3w = __expf((m3 - ms) * SCALEF);
    float lt = c0w * cml[0][1][q] + c1w * cml[1][1][q]
             + c2w * cml[2][1][q] + c3w * cml[3][1][q];
    f32x4 o0 = *(const f32x4*)&co[0][q][d0];
    f32x4 o1 = *(const f32x4*)&co[1][q][d0];
    f32x4 o2 = *(const f32x4*)&co[2][q][d0];
    f32x4 o3 = *(const f32x4*)&co[3][q][d0];
    float inv = __builtin_amdgcn_rcpf(lt);
    u16x4 st;
#pragma unroll
    for (int j = 0; j < 4; ++j)
        st[j] = f2bf((c0w * o0[j] + c1w * o1[j] + c2w * o2[j] + c3w * o3[j]) * inv);
    *(u16x4*)&XO[(long)(b * 512 + qg + q) * 1024 + h * 64 + d0] = st;
}

// ---------------------------------------------------------------------------
extern "C" void kernel_launch(void* const* d_in, const int* in_sizes, int n_in,
                              void* d_out, int out_size, void* d_ws, size_t ws_size,
                              hipStream_t stream)
{
    const float* q   = (const float*)d_in[0];
    const float* key = (const float*)d_in[1];
    const float* val = (const float*)d_in[2];
    const float* W   = (const float*)d_in[3];
    const float* ipb = (const float*)d_in[4];
    const float* ow  = (const float*)d_in[5];
    const float* ob  = (const float*)d_in[6];
    float* out = (float*)d_out;
    char* w = (char*)d_ws;

    // Workspace layout (bytes). Total 90,177,536 B (same as passing r11-r16).
    __half* PSIG  = (__half*)(w);                 // 32 MiB (64,512,512) fp16 sigmoid(phi)
    __half* ALPHA = (__half*)(w + 33554432);      // 32 MiB (64,512,512) fp16 linear alpha
    u16*    XQAQ  = (u16*)(w + 67108864);         // 8 MiB  (2048,2048) bf16
    u16*    XK    = (u16*)(w + 75497472);         // 4 MiB  (4*512,1024) bf16 (k<512 only)
    u16*    VT    = (u16*)(w + 79691776);         // 4 MiB  (64,64,512) bf16
    u16*    XO    = (u16*)(w + 83886080);         // 4 MiB  (2048,1024) bf16
    u16*    OWBF  = (u16*)(w + 88080384);         // 2 MiB  (1024,1024) bf16
    // Overlays inside PSIG+ALPHA region (dead before phi GEMM writes):
    u16* QBF = (u16*)(w);                         // 4 MiB
    u16* KBF = (u16*)(w + 4194304);               // 8 MiB
    u16* VBF = (u16*)(w + 12582912);              // 8 MiB
    u16* WBF = (u16*)(w + 20971520);              // 8 MiB (ends at 28 MiB < 32)

    dim3 blk(256);

    // 0) f32 -> bf16 copies (single fused dispatch)
    cvt_all_k<<<dim3(15360), blk, 0, stream>>>(
        q, key, val, W, ow, QBF, KBF, VBF, WBF, OWBF);

    // 1) XQAQ = q @ W[0:2048]^T + ipb[0:2048]  (cols 0..1023 = xqa, 1024.. = xq)
    mfma_nt<128, 128, 0><<<dim3(16, 16, 1), blk, 0, stream>>>(
        QBF, WBF, XQAQ, ipb, 1024, 1024, 1024, 2048, 0, 0, 0, 0, 0, 0, 1);
    // 2) XK = key[:, :512] @ Wk^T + bk   (only k<512 tokens reachable)
    mfma_nt<128, 128, 0><<<dim3(8, 4, 4), blk, 0, stream>>>(
        KBF, WBF + 2097152, XK, ipb + 2048, 1024, 1024, 1024, 1024,
        1048576L, 0, 0, 0, 524288L, 0, 1);
    // 3) VT = transpose(val[:, :512] @ Wv^T + bv): VT[(b16h)*64+d][k<512]
    mfma_nt<128, 128, 4><<<dim3(8, 4, 4), blk, 0, stream>>>(
        VBF, WBF + 3145728, VT, ipb + 3072, 1024, 1024, 1024, 0,
        1048576L, 0, 0, 0, 0, 0, 1);
    // 4) PSIG[n][q][k<512] = sigmoid(CLAMP * tanh(xqa_q . xk_k)); triangular
    mfma_nt<128, 128, 1, true><<<dim3(4, 4, 64), blk, 0, stream>>>(
        XQAQ, XK, PSIG, nullptr, 64, 2048, 1024, 512,
        1048576L, 64, 524288L, 64, 4194304L, 262144L, 16);

    // 5) monotonic DP: 32 blocks x 1 wave x 2 interleaved slices (ILP)
    mono_dp_k<<<dim3(32), dim3(64), 0, stream>>>(PSIG, ALPHA);

    // 6) fused attention (scores + alpha-softmax + PV), all 512 q
    fused_attn_k<<<dim3(64, 32, 1), blk, 0, stream>>>(XQAQ, XK, VT, ALPHA, XO);

    // 7) out = XO @ ow^T + ob  (f32)
    mfma_nt<128, 128, 3><<<dim3(8, 16, 1), blk, 0, stream>>>(
        XO, OWBF, out, ob, 1024, 1024, 1024, 1024, 0, 0, 0, 0, 0, 0, 1);
}

// Round 19
// 227.223 us; speedup vs baseline: 1.1557x; 1.1557x over previous
//
#include <hip/hip_runtime.h>
#include <hip/hip_fp16.h>
#include <hip/hip_bf16.h>
#include <math.h>

typedef unsigned short u16;
typedef __attribute__((ext_vector_type(8))) short bf16x8;
typedef __attribute__((ext_vector_type(8))) unsigned short u16x8;
typedef __attribute__((ext_vector_type(4))) unsigned short u16x4;
typedef __attribute__((ext_vector_type(4))) float f32x4;

static constexpr float CLAMPF = 3.8918202981106265f; // -log(1/0.98 - 1)
static constexpr float SCALEF = 0.125f;              // 1/sqrt(64)
static constexpr float ASCALE = 16384.f;             // 2^14 alpha storage scale

__device__ __forceinline__ u16 f2bf(float x) {
    __hip_bfloat16 h = __float2bfloat16(x);
    return *reinterpret_cast<u16*>(&h);
}

// ---------------------------------------------------------------------------
// bf16 MFMA GEMM, NT form: C[m][n] = sum_k A[m][k]*B[n][k]  (+ epilogue)
// CVA/CVB: operand is f32 in global; converted to bf16 in-register during
// staging (removes the separate cvt pass; each input element is read exactly
// once by its consumer GEMM anyway).
// EPI: 0=bf16(+opt bias), 1=fp16 sigmoid(CLAMP*tanh(x)), 3=f32+bias,
//      4=bf16 V-transpose store VT[((b*16+h)*64+d)*512 + k] + bias
// TRI: phi triangular skip — tiles with k-tile > q-tile are zero-filled.
// ---------------------------------------------------------------------------
template<int TM, int TN, int EPI, bool TRI = false, bool CVA = false, bool CVB = false>
__global__ __launch_bounds__(256)
void mfma_nt(const void* __restrict__ Ag, const void* __restrict__ Bg,
             void* __restrict__ Cg, const float* __restrict__ bias,
             int K, int lda, int ldb, int ldc,
             long sAb, long sAh, long sBb, long sBh, long sCb, long sCh,
             int hdiv)
{
    __shared__ u16 As[TM * 64];
    __shared__ u16 Bs[TN * 64];

    int z = blockIdx.z;
    int b = z / hdiv, h = z % hdiv;
    const float* A32 = (const float*)Ag + (long)b * sAb + (long)h * sAh;
    const u16*   A16 = (const u16*)Ag + (long)b * sAb + (long)h * sAh;
    const float* B32 = (const float*)Bg + (long)b * sBb + (long)h * sBh;
    const u16*   B16 = (const u16*)Bg + (long)b * sBb + (long)h * sBh;

    int tid = threadIdx.x;
    int bm = blockIdx.y * TM, bn = blockIdx.x * TN;

    constexpr int AC = TM / 32;
    constexpr int BC = TN / 32;
    int srow = tid >> 3;          // 0..31
    int scol = (tid & 7) * 8;     // 0..56

    int wid = tid >> 6, lane = tid & 63;
    int wr = wid >> 1, wc = wid & 1;
    constexpr int MI = TM / 32;
    constexpr int NI = TN / 32;
    int arow0 = wr * (TM / 2) + (lane & 15);
    int bcol0 = wc * (TN / 2) + (lane & 15);
    int koff = (lane >> 4) * 8;

    if constexpr (TRI) {
        if (blockIdx.x > blockIdx.y) {   // strictly upper triangle: zero-fill
            __half* C = (__half*)Cg + (long)b * sCb + (long)h * sCh;
            int rb = bm + wr * (TM / 2) + (lane >> 4) * 4;
            int cb = bn + wc * (TN / 2) + (lane & 15);
            __half z16 = __float2half(0.f);
#pragma unroll
            for (int mi = 0; mi < MI; ++mi)
#pragma unroll
                for (int ni = 0; ni < NI; ++ni)
#pragma unroll
                    for (int r = 0; r < 4; ++r)
                        C[(long)(rb + 16 * mi + r) * ldc + cb + 16 * ni] = z16;
            return;
        }
    }

    f32x4 acc[MI][NI];
#pragma unroll
    for (int i = 0; i < MI; ++i)
#pragma unroll
        for (int j = 0; j < NI; ++j) acc[i][j] = (f32x4){0.f, 0.f, 0.f, 0.f};

    for (int kt = 0; kt < K; kt += 64) {
        u16x8 av[AC], bv[BC];
#pragma unroll
        for (int c = 0; c < AC; ++c) {
            long ro = (long)(bm + srow + 32 * c) * lda + kt + scol;
            if constexpr (CVA) {
                float4 v0 = *(const float4*)(A32 + ro);
                float4 v1 = *(const float4*)(A32 + ro + 4);
                u16x8 t;
                t[0] = f2bf(v0.x); t[1] = f2bf(v0.y); t[2] = f2bf(v0.z); t[3] = f2bf(v0.w);
                t[4] = f2bf(v1.x); t[5] = f2bf(v1.y); t[6] = f2bf(v1.z); t[7] = f2bf(v1.w);
                av[c] = t;
            } else {
                av[c] = *(const u16x8*)(A16 + ro);
            }
        }
#pragma unroll
        for (int c = 0; c < BC; ++c) {
            long ro = (long)(bn + srow + 32 * c) * ldb + kt + scol;
            if constexpr (CVB) {
                float4 v0 = *(const float4*)(B32 + ro);
                float4 v1 = *(const float4*)(B32 + ro + 4);
                u16x8 t;
                t[0] = f2bf(v0.x); t[1] = f2bf(v0.y); t[2] = f2bf(v0.z); t[3] = f2bf(v0.w);
                t[4] = f2bf(v1.x); t[5] = f2bf(v1.y); t[6] = f2bf(v1.z); t[7] = f2bf(v1.w);
                bv[c] = t;
            } else {
                bv[c] = *(const u16x8*)(B16 + ro);
            }
        }
        __syncthreads();
#pragma unroll
        for (int c = 0; c < AC; ++c)
            *(u16x8*)&As[(srow + 32 * c) * 64 + scol] = av[c];
#pragma unroll
        for (int c = 0; c < BC; ++c)
            *(u16x8*)&Bs[(srow + 32 * c) * 64 + scol] = bv[c];
        __syncthreads();

#pragma unroll
        for (int ks = 0; ks < 2; ++ks) {
            bf16x8 af[MI], bfr[NI];
#pragma unroll
            for (int mi = 0; mi < MI; ++mi)
                af[mi] = *(const bf16x8*)&As[(arow0 + 16 * mi) * 64 + ks * 32 + koff];
#pragma unroll
            for (int ni = 0; ni < NI; ++ni)
                bfr[ni] = *(const bf16x8*)&Bs[(bcol0 + 16 * ni) * 64 + ks * 32 + koff];
#pragma unroll
            for (int mi = 0; mi < MI; ++mi)
#pragma unroll
                for (int ni = 0; ni < NI; ++ni)
                    acc[mi][ni] = __builtin_amdgcn_mfma_f32_16x16x32_bf16(
                        af[mi], bfr[ni], acc[mi][ni], 0, 0, 0);
        }
    }

    // Epilogue
    int rbase = bm + wr * (TM / 2) + (lane >> 4) * 4;
    int cbase = bn + wc * (TN / 2) + (lane & 15);
#pragma unroll
    for (int mi = 0; mi < MI; ++mi) {
#pragma unroll
        for (int ni = 0; ni < NI; ++ni) {
            int m0 = rbase + 16 * mi;
            int n = cbase + 16 * ni;
            if constexpr (EPI == 0) {
                u16* C = (u16*)Cg + (long)b * sCb + (long)h * sCh;
                float bvv = bias ? bias[n] : 0.f;
#pragma unroll
                for (int r = 0; r < 4; ++r)
                    C[(long)(m0 + r) * ldc + n] = f2bf(acc[mi][ni][r] + bvv);
            } else if constexpr (EPI == 1) {
                __half* C = (__half*)Cg + (long)b * sCb + (long)h * sCh;
#pragma unroll
                for (int r = 0; r < 4; ++r) {
                    float x = acc[mi][ni][r];
                    float e2 = __expf(2.f * x);
                    float tv = CLAMPF - (2.f * CLAMPF) * __builtin_amdgcn_rcpf(e2 + 1.f);
                    float pv = __builtin_amdgcn_rcpf(1.f + __expf(-tv));
                    C[(long)(m0 + r) * ldc + n] = __float2half(pv);
                }
            } else if constexpr (EPI == 3) {
                float* C = (float*)Cg + (long)b * sCb + (long)h * sCh;
                float bvv = bias[n];
#pragma unroll
                for (int r = 0; r < 4; ++r)
                    C[(long)(m0 + r) * ldc + n] = acc[mi][ni][r] + bvv;
            } else { // EPI == 4: VT[((b*16 + n/64)*64 + n%64)*512 + k], k = m0+r
                u16* C = (u16*)Cg;
                float bvv = bias[n];
                long vaddr = ((long)(b * 16 + (n >> 6)) * 64 + (n & 63)) * 512 + m0;
                u16x4 pk;
                pk.x = f2bf(acc[mi][ni][0] + bvv);
                pk.y = f2bf(acc[mi][ni][1] + bvv);
                pk.z = f2bf(acc[mi][ni][2] + bvv);
                pk.w = f2bf(acc[mi][ni][3] + bvv);
                *(u16x4*)(C + vaddr) = pk;
            }
        }
    }
}

// ---------------------------------------------------------------------------
// Monotonic DP, LINEAR probability domain (scaled 2^14, mass-conserving).
// TRIANGULAR 512x512 (alpha==0 for k>q; TQ<TK so k<512 only). One WAVE per
// (b,h) slice; lane owns 8 contiguous k-rows; shift via one shfl_up. No LDS,
// no barriers. Depth-8 named-register prefetch. (r11's best-measured body:
// r12-r18 showed depth-16, DPP shuffles, store batching, 8-wave blocks and
// 2-slice ILP are all neutral-to-worse — the wave is cadence-bound.)
// c[i] = a[i]*(1-p[i]); a'[0]=fma(a0,p0,shfl_up(c7)); a'[i]=fma(a,p,c[i-1]).
// ---------------------------------------------------------------------------
#define DPL8(J) (*(const uint4*)(p + (long)min((J), 510) * 512 + k0))

#define DSTEP(PC, J) do { \
    const __half2* hp = (const __half2*)&(PC); \
    float pv[8]; \
    { float2 q01 = __half22float2(hp[0]); pv[0] = q01.x; pv[1] = q01.y; } \
    { float2 q23 = __half22float2(hp[1]); pv[2] = q23.x; pv[3] = q23.y; } \
    { float2 q45 = __half22float2(hp[2]); pv[4] = q45.x; pv[5] = q45.y; } \
    { float2 q67 = __half22float2(hp[3]); pv[6] = q67.x; pv[7] = q67.y; } \
    float c[8]; \
    _Pragma("unroll") \
    for (int r = 0; r < 8; ++r) c[r] = fmaf(-a[r], pv[r], a[r]); \
    float cp = __shfl_up(c[7], 1, 64); \
    if (lane == 0) cp = 0.f; \
    a[0] = fmaf(a[0], pv[0], cp); \
    _Pragma("unroll") \
    for (int r = 1; r < 8; ++r) a[r] = fmaf(a[r], pv[r], c[r - 1]); \
    uint4 st; \
    { __half2 h0 = __floats2half2_rn(a[0], a[1]), h1 = __floats2half2_rn(a[2], a[3]); \
      st.x = *(unsigned*)&h0; st.y = *(unsigned*)&h1; } \
    { __half2 h2 = __floats2half2_rn(a[4], a[5]), h3 = __floats2half2_rn(a[6], a[7]); \
      st.z = *(unsigned*)&h2; st.w = *(unsigned*)&h3; } \
    *(uint4*)(al + (long)(J) * 512 + k0) = st; \
} while (0)

__global__ __launch_bounds__(64)
void mono_dp_k(const __half* __restrict__ P, __half* __restrict__ AL)
{
    int n = blockIdx.x;
    int lane = threadIdx.x;                 // 0..63
    const __half* p = P + (long)n * 262144; // (512,512) sigmoid probs
    __half* al = AL + (long)n * 262144;     // (512,512) linear alpha (scaled)
    int k0 = lane * 8;

    float a[8];
#pragma unroll
    for (int r = 0; r < 8; ++r) a[r] = 0.f;
    if (lane == 0) a[0] = ASCALE;
    {   // column 0 = init distribution
        uint4 st;
        __half2 h0 = __floats2half2_rn(a[0], a[1]), h1 = __floats2half2_rn(a[2], a[3]);
        __half2 h2 = __floats2half2_rn(a[4], a[5]), h3 = __floats2half2_rn(a[6], a[7]);
        st.x = *(unsigned*)&h0; st.y = *(unsigned*)&h1;
        st.z = *(unsigned*)&h2; st.w = *(unsigned*)&h3;
        *(uint4*)(al + k0) = st;
    }

    // iteration j consumes p column j-1 (cols 0..510); depth-8 prefetch
    int j = 1;
    uint4 f0 = DPL8(0), f1 = DPL8(1), f2 = DPL8(2), f3 = DPL8(3);
    uint4 f4 = DPL8(4), f5 = DPL8(5), f6 = DPL8(6), f7 = DPL8(7);

    while (j + 7 < 512) {
        DSTEP(f0, j); f0 = DPL8(j + 7); ++j;
        DSTEP(f1, j); f1 = DPL8(j + 7); ++j;
        DSTEP(f2, j); f2 = DPL8(j + 7); ++j;
        DSTEP(f3, j); f3 = DPL8(j + 7); ++j;
        DSTEP(f4, j); f4 = DPL8(j + 7); ++j;
        DSTEP(f5, j); f5 = DPL8(j + 7); ++j;
        DSTEP(f6, j); f6 = DPL8(j + 7); ++j;
        DSTEP(f7, j); f7 = DPL8(j + 7); ++j;
    }
    while (j < 512) {
        DSTEP(f0, j);
        f0 = f1; f1 = f2; f2 = f3; f3 = f4; f4 = f5; f5 = f6; f6 = f7;
        ++j;
    }
}

// ---------------------------------------------------------------------------
// Fused attention, k < 512 only (alpha == 0 beyond), 4-way k-split of 128.
// grid (64 n, 32 q-groups); block = 4 waves; wave w handles 16 q x 128 k.
// Single k-tile per wave -> no online rescale. Wave skipped entirely if its
// k-range > qg+15 (alpha all zero there). Partials combined in LDS.
// ---------------------------------------------------------------------------
__global__ __launch_bounds__(256, 4)
void fused_attn_k(const u16* __restrict__ XQAQ, const u16* __restrict__ XK,
                  const u16* __restrict__ VT, const __half* __restrict__ AL,
                  u16* __restrict__ XO)
{
    __shared__ u16 wtile[4][2048];     // per-wave 16q x 128k bf16 (swizzled)
    __shared__ float co[4][16][64];    // per-wave partial O (q, d)
    __shared__ float cml[4][2][16];    // per-wave m, l per q

    int n = blockIdx.x; int b = n >> 4, h = n & 15;
    int tid = threadIdx.x, wave = tid >> 6, lane = tid & 63;
    int l15 = lane & 15, l4 = lane >> 4;
    int qg = blockIdx.y * 16;          // q base within 512
    u16* wlds = wtile[wave];
    int swz = (l15 & 7) << 3;

    float m = -3.0e38f, lsum = 0.f;
    f32x4 o[4];
#pragma unroll
    for (int df = 0; df < 4; ++df) o[df] = (f32x4){0.f, 0.f, 0.f, 0.f};

    if (wave * 128 < qg + 16) {        // triangular: this wave's k-range has mass
        // Q B-frags (col=q=l15)
        const u16* qbase = XQAQ + (long)(b * 512 + qg + l15) * 2048 + 1024 + h * 64 + l4 * 8;
        bf16x8 qf0 = *(const bf16x8*)(qbase);
        bf16x8 qf1 = *(const bf16x8*)(qbase + 32);

        const u16* kbase = XK + (long)(b * 512 + wave * 128 + l15) * 1024 + h * 64 + l4 * 8;
        const __half* abase = AL + (long)(n * 512 + qg + l15) * 512 + wave * 128 + l4 * 4;
        const u16* vbase = VT + (long)(n * 64 + l15) * 512 + wave * 128 + l4 * 8;

        // alpha regs (q=l15, k = wave*128 + kf*16 + l4*4 + r)
        uint2 areg[8];
#pragma unroll
        for (int kf = 0; kf < 8; ++kf)
            areg[kf] = *(const uint2*)(abase + kf * 16);

        // scores: s[kf][r] for q=l15, k = wave*128 + kf*16 + l4*4 + r
        f32x4 s[8];
#pragma unroll
        for (int kf = 0; kf < 8; ++kf) {
            const u16* kb = kbase + (long)(kf * 16) * 1024;
            bf16x8 k0 = *(const bf16x8*)kb;
            bf16x8 k1 = *(const bf16x8*)(kb + 32);
            f32x4 acc = (f32x4){0.f, 0.f, 0.f, 0.f};
            acc = __builtin_amdgcn_mfma_f32_16x16x32_bf16(k0, qf0, acc, 0, 0, 0);
            acc = __builtin_amdgcn_mfma_f32_16x16x32_bf16(k1, qf1, acc, 0, 0, 0);
            s[kf] = acc;
        }

        // tile max per q (in-lane, then across l4 groups)
        float mt = -3.0e38f;
#pragma unroll
        for (int kf = 0; kf < 8; ++kf)
            mt = fmaxf(mt, fmaxf(fmaxf(s[kf][0], s[kf][1]), fmaxf(s[kf][2], s[kf][3])));
        mt = fmaxf(mt, __shfl_xor(mt, 16, 64));
        mt = fmaxf(mt, __shfl_xor(mt, 32, 64));
        m = mt;
        float negm = -mt * SCALEF;

        // w = alpha * exp(SCALE*(s - m)), accumulate l, store swizzled LDS
#pragma unroll
        for (int kf = 0; kf < 8; ++kf) {
            float2 a01 = __half22float2(*(__half2*)&areg[kf].x);
            float2 a23 = __half22float2(*(__half2*)&areg[kf].y);
            float w0 = a01.x * __expf(fmaf(s[kf][0], SCALEF, negm));
            float w1 = a01.y * __expf(fmaf(s[kf][1], SCALEF, negm));
            float w2 = a23.x * __expf(fmaf(s[kf][2], SCALEF, negm));
            float w3 = a23.y * __expf(fmaf(s[kf][3], SCALEF, negm));
            lsum += (w0 + w1) + (w2 + w3);
            u16x4 wp; wp.x = f2bf(w0); wp.y = f2bf(w1); wp.z = f2bf(w2); wp.w = f2bf(w3);
            *(u16x4*)&wlds[(l15 * 128 + kf * 16 + l4 * 4) ^ swz] = wp;
        }

        // PV over this 128-k tile
#pragma unroll
        for (int ks2 = 0; ks2 < 4; ++ks2) {
            bf16x8 wf = *(const bf16x8*)&wlds[(l15 * 128 + ks2 * 32 + l4 * 8) ^ swz];
#pragma unroll
            for (int df = 0; df < 4; ++df) {
                const u16* vb = vbase + (long)(df * 16) * 512 + ks2 * 32;
                bf16x8 vf = *(const bf16x8*)vb;
                o[df] = __builtin_amdgcn_mfma_f32_16x16x32_bf16(wf, vf, o[df], 0, 0, 0);
            }
        }

        // full-row l per q
        lsum += __shfl_xor(lsum, 16, 64);
        lsum += __shfl_xor(lsum, 32, 64);
    }

    if (lane < 16) { cml[wave][0][l15] = m; cml[wave][1][l15] = lsum; }
#pragma unroll
    for (int df = 0; df < 4; ++df)
#pragma unroll
        for (int r = 0; r < 4; ++r)
            co[wave][l4 * 4 + r][df * 16 + l15] = o[df][r];
    __syncthreads();

    // combine 4 k-split partials; thread handles (q = tid>>4, d0 = (tid&15)*4)
    int q = tid >> 4, d0 = (tid & 15) * 4;
    float m0 = cml[0][0][q], m1 = cml[1][0][q], m2 = cml[2][0][q], m3 = cml[3][0][q];
    float ms = fmaxf(fmaxf(m0, m1), fmaxf(m2, m3));
    float c0w = __expf((m0 - ms) * SCALEF), c1w = __expf((m1 - ms) * SCALEF);
    float c2w = __expf((m2 - ms) * SCALEF), c3w = __expf((m3 - ms) * SCALEF);
    float lt = c0w * cml[0][1][q] + c1w * cml[1][1][q]
             + c2w * cml[2][1][q] + c3w * cml[3][1][q];
    f32x4 o0 = *(const f32x4*)&co[0][q][d0];
    f32x4 o1 = *(const f32x4*)&co[1][q][d0];
    f32x4 o2 = *(const f32x4*)&co[2][q][d0];
    f32x4 o3 = *(const f32x4*)&co[3][q][d0];
    float inv = __builtin_amdgcn_rcpf(lt);
    u16x4 st;
#pragma unroll
    for (int j = 0; j < 4; ++j)
        st[j] = f2bf((c0w * o0[j] + c1w * o1[j] + c2w * o2[j] + c3w * o3[j]) * inv);
    *(u16x4*)&XO[(long)(b * 512 + qg + q) * 1024 + h * 64 + d0] = st;
}

// ---------------------------------------------------------------------------
extern "C" void kernel_launch(void* const* d_in, const int* in_sizes, int n_in,
                              void* d_out, int out_size, void* d_ws, size_t ws_size,
                              hipStream_t stream)
{
    const float* q   = (const float*)d_in[0];
    const float* key = (const float*)d_in[1];
    const float* val = (const float*)d_in[2];
    const float* W   = (const float*)d_in[3];
    const float* ipb = (const float*)d_in[4];
    const float* ow  = (const float*)d_in[5];
    const float* ob  = (const float*)d_in[6];
    float* out = (float*)d_out;
    char* w = (char*)d_ws;

    // Workspace layout (bytes). Total 88,080,384 B (84 MiB).
    __half* PSIG  = (__half*)(w);                 // 32 MiB (64,512,512) fp16 sigmoid(phi)
    __half* ALPHA = (__half*)(w + 33554432);      // 32 MiB (64,512,512) fp16 linear alpha
    u16*    XQAQ  = (u16*)(w + 67108864);         // 8 MiB  (2048,2048) bf16
    u16*    XK    = (u16*)(w + 75497472);         // 4 MiB  (4*512,1024) bf16 (k<512 only)
    u16*    VT    = (u16*)(w + 79691776);         // 4 MiB  (64,64,512) bf16
    u16*    XO    = (u16*)(w + 83886080);         // 4 MiB  (2048,1024) bf16

    dim3 blk(256);

    // 1) XQAQ = q @ W[0:2048]^T + ipb[0:2048]  (f32 inputs, inline cvt)
    mfma_nt<128, 128, 0, false, true, true><<<dim3(16, 16, 1), blk, 0, stream>>>(
        q, W, XQAQ, ipb, 1024, 1024, 1024, 2048, 0, 0, 0, 0, 0, 0, 1);
    // 2) XK = key[:, :512] @ Wk^T + bk   (f32 inputs, inline cvt)
    mfma_nt<128, 128, 0, false, true, true><<<dim3(8, 4, 4), blk, 0, stream>>>(
        key, W + 2097152, XK, ipb + 2048, 1024, 1024, 1024, 1024,
        1048576L, 0, 0, 0, 524288L, 0, 1);
    // 3) VT = transpose(val[:, :512] @ Wv^T + bv)  (f32 inputs, inline cvt)
    mfma_nt<128, 128, 4, false, true, true><<<dim3(8, 4, 4), blk, 0, stream>>>(
        val, W + 3145728, VT, ipb + 3072, 1024, 1024, 1024, 0,
        1048576L, 0, 0, 0, 0, 0, 1);
    // 4) PSIG[n][q][k<512] = sigmoid(CLAMP * tanh(xqa_q . xk_k)); triangular
    mfma_nt<128, 128, 1, true><<<dim3(4, 4, 64), blk, 0, stream>>>(
        XQAQ, XK, PSIG, nullptr, 64, 2048, 1024, 512,
        1048576L, 64, 524288L, 64, 4194304L, 262144L, 16);

    // 5) monotonic DP (single dispatch, 512x512 triangular, barrier-free)
    mono_dp_k<<<dim3(64), dim3(64), 0, stream>>>(PSIG, ALPHA);

    // 6) fused attention (scores + alpha-softmax + PV), all 512 q
    fused_attn_k<<<dim3(64, 32, 1), blk, 0, stream>>>(XQAQ, XK, VT, ALPHA, XO);

    // 7) out = XO @ ow^T + ob  (A bf16, B f32 inline cvt)
    mfma_nt<128, 128, 3, false, false, true><<<dim3(8, 16, 1), blk, 0, stream>>>(
        XO, ow, out, ob, 1024, 1024, 1024, 1024, 0, 0, 0, 0, 0, 0, 1);
}

// Round 20
// 185.400 us; speedup vs baseline: 1.4165x; 1.2256x over previous
//
#include <hip/hip_runtime.h>
#include <hip/hip_fp16.h>
#include <hip/hip_bf16.h>
#include <math.h>

typedef unsigned short u16;
typedef __attribute__((ext_vector_type(8))) short bf16x8;
typedef __attribute__((ext_vector_type(8))) unsigned short u16x8;
typedef __attribute__((ext_vector_type(4))) unsigned short u16x4;
typedef __attribute__((ext_vector_type(4))) float f32x4;

static constexpr float CLAMPF = 3.8918202981106265f; // -log(1/0.98 - 1)
static constexpr float SCALEF = 0.125f;              // 1/sqrt(64)
static constexpr float ASCALE = 16384.f;             // 2^14 alpha storage scale

__device__ __forceinline__ u16 f2bf(float x) {
    __hip_bfloat16 h = __float2bfloat16(x);
    return *reinterpret_cast<u16*>(&h);
}

// ---------------------------------------------------------------------------
// Fused f32 -> bf16 conversion for all 5 inputs (one dispatch).
// ---------------------------------------------------------------------------
__global__ __launch_bounds__(256)
void cvt_all_k(const float* __restrict__ q, const float* __restrict__ key,
               const float* __restrict__ val, const float* __restrict__ W,
               const float* __restrict__ ow,
               u16* __restrict__ QBF, u16* __restrict__ KBF,
               u16* __restrict__ VBF, u16* __restrict__ WBF,
               u16* __restrict__ OWBF)
{
    long i = (long)blockIdx.x * 256 + threadIdx.x;
    const float* src; u16* dst; long off;
    if (i < 524288)       { src = q;   dst = QBF;  off = i; }
    else if (i < 1572864) { src = key; dst = KBF;  off = i - 524288; }
    else if (i < 2621440) { src = val; dst = VBF;  off = i - 1572864; }
    else if (i < 3670016) { src = W;   dst = WBF;  off = i - 2621440; }
    else if (i < 3932160) { src = ow;  dst = OWBF; off = i - 3670016; }
    else return;
    float4 v = ((const float4*)src)[off];
    u16x4 o; o.x = f2bf(v.x); o.y = f2bf(v.y); o.z = f2bf(v.z); o.w = f2bf(v.w);
    ((u16x4*)dst)[off] = o;
}

// ---------------------------------------------------------------------------
// bf16 MFMA GEMM body (device fn; LDS passed in), NT form:
// C[m][n] = sum_k A[m][k]*B[n][k]  (+ epilogue)
// EPI: 0=bf16(+opt bias), 1=fp16 sigmoid(CLAMP*tanh(x)), 3=f32+bias,
//      4=bf16 V-transpose store VT[((b*16+h)*64+d)*512 + k] + bias
// TRI: phi triangular skip — tiles with k-tile > q-tile are zero-filled.
// ---------------------------------------------------------------------------
template<int TM, int TN, int EPI, bool TRI>
__device__ __forceinline__
void mfma_body(u16* As, u16* Bs, int bx, int by, int bz,
               const u16* __restrict__ Ag, const u16* __restrict__ Bg,
               void* __restrict__ Cg, const float* __restrict__ bias,
               int K, int lda, int ldb, int ldc,
               long sAb, long sAh, long sBb, long sBh, long sCb, long sCh,
               int hdiv)
{
    int b = bz / hdiv, h = bz % hdiv;
    const u16* A = Ag + (long)b * sAb + (long)h * sAh;
    const u16* B = Bg + (long)b * sBb + (long)h * sBh;

    int tid = threadIdx.x;
    int bm = by * TM, bn = bx * TN;

    constexpr int AC = TM / 32;
    constexpr int BC = TN / 32;
    int srow = tid >> 3;          // 0..31
    int scol = (tid & 7) * 8;     // 0..56

    int wid = tid >> 6, lane = tid & 63;
    int wr = wid >> 1, wc = wid & 1;
    constexpr int MI = TM / 32;
    constexpr int NI = TN / 32;
    int arow0 = wr * (TM / 2) + (lane & 15);
    int bcol0 = wc * (TN / 2) + (lane & 15);
    int koff = (lane >> 4) * 8;

    if constexpr (TRI) {
        if (bx > by) {   // strictly upper triangle: zero-fill
            __half* C = (__half*)Cg + (long)b * sCb + (long)h * sCh;
            int rb = bm + wr * (TM / 2) + (lane >> 4) * 4;
            int cb = bn + wc * (TN / 2) + (lane & 15);
            __half z16 = __float2half(0.f);
#pragma unroll
            for (int mi = 0; mi < MI; ++mi)
#pragma unroll
                for (int ni = 0; ni < NI; ++ni)
#pragma unroll
                    for (int r = 0; r < 4; ++r)
                        C[(long)(rb + 16 * mi + r) * ldc + cb + 16 * ni] = z16;
            return;
        }
    }

    f32x4 acc[MI][NI];
#pragma unroll
    for (int i = 0; i < MI; ++i)
#pragma unroll
        for (int j = 0; j < NI; ++j) acc[i][j] = (f32x4){0.f, 0.f, 0.f, 0.f};

    for (int kt = 0; kt < K; kt += 64) {
        u16x8 av[AC], bv[BC];
#pragma unroll
        for (int c = 0; c < AC; ++c)
            av[c] = *(const u16x8*)(A + (long)(bm + srow + 32 * c) * lda + kt + scol);
#pragma unroll
        for (int c = 0; c < BC; ++c)
            bv[c] = *(const u16x8*)(B + (long)(bn + srow + 32 * c) * ldb + kt + scol);
        __syncthreads();
#pragma unroll
        for (int c = 0; c < AC; ++c)
            *(u16x8*)&As[(srow + 32 * c) * 64 + scol] = av[c];
#pragma unroll
        for (int c = 0; c < BC; ++c)
            *(u16x8*)&Bs[(srow + 32 * c) * 64 + scol] = bv[c];
        __syncthreads();

#pragma unroll
        for (int ks = 0; ks < 2; ++ks) {
            bf16x8 af[MI], bfr[NI];
#pragma unroll
            for (int mi = 0; mi < MI; ++mi)
                af[mi] = *(const bf16x8*)&As[(arow0 + 16 * mi) * 64 + ks * 32 + koff];
#pragma unroll
            for (int ni = 0; ni < NI; ++ni)
                bfr[ni] = *(const bf16x8*)&Bs[(bcol0 + 16 * ni) * 64 + ks * 32 + koff];
#pragma unroll
            for (int mi = 0; mi < MI; ++mi)
#pragma unroll
                for (int ni = 0; ni < NI; ++ni)
                    acc[mi][ni] = __builtin_amdgcn_mfma_f32_16x16x32_bf16(
                        af[mi], bfr[ni], acc[mi][ni], 0, 0, 0);
        }
    }

    // Epilogue
    int rbase = bm + wr * (TM / 2) + (lane >> 4) * 4;
    int cbase = bn + wc * (TN / 2) + (lane & 15);
#pragma unroll
    for (int mi = 0; mi < MI; ++mi) {
#pragma unroll
        for (int ni = 0; ni < NI; ++ni) {
            int m0 = rbase + 16 * mi;
            int n = cbase + 16 * ni;
            if constexpr (EPI == 0) {
                u16* C = (u16*)Cg + (long)b * sCb + (long)h * sCh;
                float bvv = bias ? bias[n] : 0.f;
#pragma unroll
                for (int r = 0; r < 4; ++r)
                    C[(long)(m0 + r) * ldc + n] = f2bf(acc[mi][ni][r] + bvv);
            } else if constexpr (EPI == 1) {
                __half* C = (__half*)Cg + (long)b * sCb + (long)h * sCh;
#pragma unroll
                for (int r = 0; r < 4; ++r) {
                    float x = acc[mi][ni][r];
                    float e2 = __expf(2.f * x);
                    float tv = CLAMPF - (2.f * CLAMPF) * __builtin_amdgcn_rcpf(e2 + 1.f);
                    float pv = __builtin_amdgcn_rcpf(1.f + __expf(-tv));
                    C[(long)(m0 + r) * ldc + n] = __float2half(pv);
                }
            } else if constexpr (EPI == 3) {
                float* C = (float*)Cg + (long)b * sCb + (long)h * sCh;
                float bvv = bias[n];
#pragma unroll
                for (int r = 0; r < 4; ++r)
                    C[(long)(m0 + r) * ldc + n] = acc[mi][ni][r] + bvv;
            } else { // EPI == 4: VT[((b*16 + n/64)*64 + n%64)*512 + k], k = m0+r
                u16* C = (u16*)Cg;
                float bvv = bias[n];
                long vaddr = ((long)(b * 16 + (n >> 6)) * 64 + (n & 63)) * 512 + m0;
                u16x4 pk;
                pk.x = f2bf(acc[mi][ni][0] + bvv);
                pk.y = f2bf(acc[mi][ni][1] + bvv);
                pk.z = f2bf(acc[mi][ni][2] + bvv);
                pk.w = f2bf(acc[mi][ni][3] + bvv);
                *(u16x4*)(C + vaddr) = pk;
            }
        }
    }
}

template<int TM, int TN, int EPI, bool TRI = false>
__global__ __launch_bounds__(256)
void mfma_nt(const u16* __restrict__ Ag, const u16* __restrict__ Bg,
             void* __restrict__ Cg, const float* __restrict__ bias,
             int K, int lda, int ldb, int ldc,
             long sAb, long sAh, long sBb, long sBh, long sCb, long sCh,
             int hdiv)
{
    __shared__ u16 As[TM * 64];
    __shared__ u16 Bs[TN * 64];
    mfma_body<TM, TN, EPI, TRI>(As, Bs, blockIdx.x, blockIdx.y, blockIdx.z,
                                Ag, Bg, Cg, bias, K, lda, ldb, ldc,
                                sAb, sAh, sBb, sBh, sCb, sCh, hdiv);
}

// ---------------------------------------------------------------------------
// Monotonic DP (r11/r15 best body) FUSED with XK and VT projections:
// grid 320 x 256 thr. Blocks 0-63: DP slice n=bid (wave 0 only).
// Blocks 64-191: XK tiles. Blocks 192-319: VT tiles — run concurrently on
// the ~192 CUs the DP leaves idle. KBF/VBF/WBF live OUTSIDE the PSIG/ALPHA
// regions (no overlay hazard with the earlier PSIG write).
// ---------------------------------------------------------------------------
#define DPL8(J) (*(const uint4*)(p + (long)min((J), 510) * 512 + k0))

#define DSTEP(PC, J) do { \
    const __half2* hp = (const __half2*)&(PC); \
    float pv[8]; \
    { float2 q01 = __half22float2(hp[0]); pv[0] = q01.x; pv[1] = q01.y; } \
    { float2 q23 = __half22float2(hp[1]); pv[2] = q23.x; pv[3] = q23.y; } \
    { float2 q45 = __half22float2(hp[2]); pv[4] = q45.x; pv[5] = q45.y; } \
    { float2 q67 = __half22float2(hp[3]); pv[6] = q67.x; pv[7] = q67.y; } \
    float c[8]; \
    _Pragma("unroll") \
    for (int r = 0; r < 8; ++r) c[r] = fmaf(-a[r], pv[r], a[r]); \
    float cp = __shfl_up(c[7], 1, 64); \
    if (lane == 0) cp = 0.f; \
    a[0] = fmaf(a[0], pv[0], cp); \
    _Pragma("unroll") \
    for (int r = 1; r < 8; ++r) a[r] = fmaf(a[r], pv[r], c[r - 1]); \
    uint4 st; \
    { __half2 h0 = __floats2half2_rn(a[0], a[1]), h1 = __floats2half2_rn(a[2], a[3]); \
      st.x = *(unsigned*)&h0; st.y = *(unsigned*)&h1; } \
    { __half2 h2 = __floats2half2_rn(a[4], a[5]), h3 = __floats2half2_rn(a[6], a[7]); \
      st.z = *(unsigned*)&h2; st.w = *(unsigned*)&h3; } \
    *(uint4*)(al + (long)(J) * 512 + k0) = st; \
} while (0)

__global__ __launch_bounds__(256)
void dp_kv_k(const __half* __restrict__ P, __half* __restrict__ AL,
             const u16* __restrict__ KBF, const u16* __restrict__ VBF,
             const u16* __restrict__ WBF, const float* __restrict__ ipb,
             u16* __restrict__ XK, u16* __restrict__ VT)
{
    __shared__ u16 As[128 * 64];
    __shared__ u16 Bs[128 * 64];
    int bid = blockIdx.x;

    if (bid >= 192) {            // VT projection tiles: (8,4,4) flattened
        int idx = bid - 192;
        mfma_body<128, 128, 4, false>(As, Bs, idx & 7, (idx >> 3) & 3, idx >> 5,
            VBF, WBF + 3145728, VT, ipb + 3072, 1024, 1024, 1024, 0,
            1048576L, 0, 0, 0, 0, 0, 1);
        return;
    }
    if (bid >= 64) {             // XK projection tiles
        int idx = bid - 64;
        mfma_body<128, 128, 0, false>(As, Bs, idx & 7, (idx >> 3) & 3, idx >> 5,
            KBF, WBF + 2097152, XK, ipb + 2048, 1024, 1024, 1024, 1024,
            1048576L, 0, 0, 0, 524288L, 0, 1);
        return;
    }

    // ---- DP: blocks 0..63, wave 0 only ----
    if (threadIdx.x >= 64) return;
    int n = bid;
    int lane = threadIdx.x;                 // 0..63
    const __half* p = P + (long)n * 262144; // (512,512) sigmoid probs
    __half* al = AL + (long)n * 262144;     // (512,512) linear alpha (scaled)
    int k0 = lane * 8;

    float a[8];
#pragma unroll
    for (int r = 0; r < 8; ++r) a[r] = 0.f;
    if (lane == 0) a[0] = ASCALE;
    {   // column 0 = init distribution
        uint4 st;
        __half2 h0 = __floats2half2_rn(a[0], a[1]), h1 = __floats2half2_rn(a[2], a[3]);
        __half2 h2 = __floats2half2_rn(a[4], a[5]), h3 = __floats2half2_rn(a[6], a[7]);
        st.x = *(unsigned*)&h0; st.y = *(unsigned*)&h1;
        st.z = *(unsigned*)&h2; st.w = *(unsigned*)&h3;
        *(uint4*)(al + k0) = st;
    }

    int j = 1;
    uint4 f0 = DPL8(0), f1 = DPL8(1), f2 = DPL8(2), f3 = DPL8(3);
    uint4 f4 = DPL8(4), f5 = DPL8(5), f6 = DPL8(6), f7 = DPL8(7);

    while (j + 7 < 512) {
        DSTEP(f0, j); f0 = DPL8(j + 7); ++j;
        DSTEP(f1, j); f1 = DPL8(j + 7); ++j;
        DSTEP(f2, j); f2 = DPL8(j + 7); ++j;
        DSTEP(f3, j); f3 = DPL8(j + 7); ++j;
        DSTEP(f4, j); f4 = DPL8(j + 7); ++j;
        DSTEP(f5, j); f5 = DPL8(j + 7); ++j;
        DSTEP(f6, j); f6 = DPL8(j + 7); ++j;
        DSTEP(f7, j); f7 = DPL8(j + 7); ++j;
    }
    while (j < 512) {
        DSTEP(f0, j);
        f0 = f1; f1 = f2; f2 = f3; f3 = f4; f4 = f5; f5 = f6; f6 = f7;
        ++j;
    }
}

// ---------------------------------------------------------------------------
// Fused attention, k < 512 only (alpha == 0 beyond), 4-way k-split of 128.
// ---------------------------------------------------------------------------
__global__ __launch_bounds__(256, 4)
void fused_attn_k(const u16* __restrict__ XQAQ, const u16* __restrict__ XK,
                  const u16* __restrict__ VT, const __half* __restrict__ AL,
                  u16* __restrict__ XO)
{
    __shared__ u16 wtile[4][2048];
    __shared__ float co[4][16][64];
    __shared__ float cml[4][2][16];

    int n = blockIdx.x; int b = n >> 4, h = n & 15;
    int tid = threadIdx.x, wave = tid >> 6, lane = tid & 63;
    int l15 = lane & 15, l4 = lane >> 4;
    int qg = blockIdx.y * 16;
    u16* wlds = wtile[wave];
    int swz = (l15 & 7) << 3;

    float m = -3.0e38f, lsum = 0.f;
    f32x4 o[4];
#pragma unroll
    for (int df = 0; df < 4; ++df) o[df] = (f32x4){0.f, 0.f, 0.f, 0.f};

    if (wave * 128 < qg + 16) {
        const u16* qbase = XQAQ + (long)(b * 512 + qg + l15) * 2048 + 1024 + h * 64 + l4 * 8;
        bf16x8 qf0 = *(const bf16x8*)(qbase);
        bf16x8 qf1 = *(const bf16x8*)(qbase + 32);

        const u16* kbase = XK + (long)(b * 512 + wave * 128 + l15) * 1024 + h * 64 + l4 * 8;
        const __half* abase = AL + (long)(n * 512 + qg + l15) * 512 + wave * 128 + l4 * 4;
        const u16* vbase = VT + (long)(n * 64 + l15) * 512 + wave * 128 + l4 * 8;

        uint2 areg[8];
#pragma unroll
        for (int kf = 0; kf < 8; ++kf)
            areg[kf] = *(const uint2*)(abase + kf * 16);

        f32x4 s[8];
#pragma unroll
        for (int kf = 0; kf < 8; ++kf) {
            const u16* kb = kbase + (long)(kf * 16) * 1024;
            bf16x8 k0 = *(const bf16x8*)kb;
            bf16x8 k1 = *(const bf16x8*)(kb + 32);
            f32x4 acc = (f32x4){0.f, 0.f, 0.f, 0.f};
            acc = __builtin_amdgcn_mfma_f32_16x16x32_bf16(k0, qf0, acc, 0, 0, 0);
            acc = __builtin_amdgcn_mfma_f32_16x16x32_bf16(k1, qf1, acc, 0, 0, 0);
            s[kf] = acc;
        }

        float mt = -3.0e38f;
#pragma unroll
        for (int kf = 0; kf < 8; ++kf)
            mt = fmaxf(mt, fmaxf(fmaxf(s[kf][0], s[kf][1]), fmaxf(s[kf][2], s[kf][3])));
        mt = fmaxf(mt, __shfl_xor(mt, 16, 64));
        mt = fmaxf(mt, __shfl_xor(mt, 32, 64));
        m = mt;
        float negm = -mt * SCALEF;

#pragma unroll
        for (int kf = 0; kf < 8; ++kf) {
            float2 a01 = __half22float2(*(__half2*)&areg[kf].x);
            float2 a23 = __half22float2(*(__half2*)&areg[kf].y);
            float w0 = a01.x * __expf(fmaf(s[kf][0], SCALEF, negm));
            float w1 = a01.y * __expf(fmaf(s[kf][1], SCALEF, negm));
            float w2 = a23.x * __expf(fmaf(s[kf][2], SCALEF, negm));
            float w3 = a23.y * __expf(fmaf(s[kf][3], SCALEF, negm));
            lsum += (w0 + w1) + (w2 + w3);
            u16x4 wp; wp.x = f2bf(w0); wp.y = f2bf(w1); wp.z = f2bf(w2); wp.w = f2bf(w3);
            *(u16x4*)&wlds[(l15 * 128 + kf * 16 + l4 * 4) ^ swz] = wp;
        }

#pragma unroll
        for (int ks2 = 0; ks2 < 4; ++ks2) {
            bf16x8 wf = *(const bf16x8*)&wlds[(l15 * 128 + ks2 * 32 + l4 * 8) ^ swz];
#pragma unroll
            for (int df = 0; df < 4; ++df) {
                const u16* vb = vbase + (long)(df * 16) * 512 + ks2 * 32;
                bf16x8 vf = *(const bf16x8*)vb;
                o[df] = __builtin_amdgcn_mfma_f32_16x16x32_bf16(wf, vf, o[df], 0, 0, 0);
            }
        }

        lsum += __shfl_xor(lsum, 16, 64);
        lsum += __shfl_xor(lsum, 32, 64);
    }

    if (lane < 16) { cml[wave][0][l15] = m; cml[wave][1][l15] = lsum; }
#pragma unroll
    for (int df = 0; df < 4; ++df)
#pragma unroll
        for (int r = 0; r < 4; ++r)
            co[wave][l4 * 4 + r][df * 16 + l15] = o[df][r];
    __syncthreads();

    int q = tid >> 4, d0 = (tid & 15) * 4;
    float m0 = cml[0][0][q], m1 = cml[1][0][q], m2 = cml[2][0][q], m3 = cml[3][0][q];
    float ms = fmaxf(fmaxf(m0, m1), fmaxf(m2, m3));
    float c0w = __expf((m0 - ms) * SCALEF), c1w = __expf((m1 - ms) * SCALEF);
    float c2w = __expf((m2 - ms) * SCALEF), c3w = __expf((m3 - ms) * SCALEF);
    float lt = c0w * cml[0][1][q] + c1w * cml[1][1][q]
             + c2w * cml[2][1][q] + c3w * cml[3][1][q];
    f32x4 o0 = *(const f32x4*)&co[0][q][d0];
    f32x4 o1 = *(const f32x4*)&co[1][q][d0];
    f32x4 o2 = *(const f32x4*)&co[2][q][d0];
    f32x4 o3 = *(const f32x4*)&co[3][q][d0];
    float inv = __builtin_amdgcn_rcpf(lt);
    u16x4 st;
#pragma unroll
    for (int j = 0; j < 4; ++j)
        st[j] = f2bf((c0w * o0[j] + c1w * o1[j] + c2w * o2[j] + c3w * o3[j]) * inv);
    *(u16x4*)&XO[(long)(b * 512 + qg + q) * 1024 + h * 64 + d0] = st;
}

// ---------------------------------------------------------------------------
extern "C" void kernel_launch(void* const* d_in, const int* in_sizes, int n_in,
                              void* d_out, int out_size, void* d_ws, size_t ws_size,
                              hipStream_t stream)
{
    const float* q   = (const float*)d_in[0];
    const float* key = (const float*)d_in[1];
    const float* val = (const float*)d_in[2];
    const float* W   = (const float*)d_in[3];
    const float* ipb = (const float*)d_in[4];
    const float* ow  = (const float*)d_in[5];
    const float* ob  = (const float*)d_in[6];
    float* out = (float*)d_out;
    char* w = (char*)d_ws;

    // Workspace layout (bytes). Total 115,343,360 B (110 MiB < known-good 132).
    // KBF/VBF/WBF are persistent (read by dp_kv_k AFTER PSIG is written), so
    // they live OUTSIDE the PSIG region; only QBF overlays PSIG (consumed by
    // the XQAQ projection before the PSIG dispatch).
    __half* PSIG  = (__half*)(w);                 // 32 MiB (64,512,512) fp16
    __half* ALPHA = (__half*)(w + 33554432);      // 32 MiB (64,512,512) fp16
    u16*    XQAQ  = (u16*)(w + 67108864);         // 8 MiB  (2048,2048) bf16
    u16*    XK    = (u16*)(w + 75497472);         // 4 MiB  (4*512,1024) bf16
    u16*    VT    = (u16*)(w + 79691776);         // 4 MiB  (64,64,512) bf16
    u16*    XO    = (u16*)(w + 83886080);         // 4 MiB  (2048,1024) bf16
    u16*    OWBF  = (u16*)(w + 88080384);         // 2 MiB  (1024,1024) bf16
    u16*    KBF   = (u16*)(w + 90177536);         // 8 MiB  (4096,1024) bf16
    u16*    VBF   = (u16*)(w + 98566144);         // 8 MiB  (4096,1024) bf16
    u16*    WBF   = (u16*)(w + 106954752);        // 8 MiB  (4096,1024) bf16
    u16*    QBF   = (u16*)(w);                    // 4 MiB overlay in PSIG

    dim3 blk(256);

    // 0) f32 -> bf16 copies (single fused dispatch)
    cvt_all_k<<<dim3(15360), blk, 0, stream>>>(
        q, key, val, W, ow, QBF, KBF, VBF, WBF, OWBF);

    // 1) XQAQ = q @ W[0:2048]^T + ipb[0:2048]
    mfma_nt<128, 128, 0><<<dim3(16, 16, 1), blk, 0, stream>>>(
        QBF, WBF, XQAQ, ipb, 1024, 1024, 1024, 2048, 0, 0, 0, 0, 0, 0, 1);
    // 2) PSIG[n][q][k<512] = sigmoid(CLAMP*tanh(xqa . xk)) — but XK isn't
    //    computed yet! PSIG uses XQAQ (A) and XK (B)... XK comes from dp_kv_k
    //    which runs AFTER. ORDER FIX: PSIG's B operand is XK — so XK must be
    //    computed BEFORE PSIG. Run a standalone XK here; dp_kv_k keeps only
    //    DP + VT (VT is only needed by attn).
    mfma_nt<128, 128, 0><<<dim3(8, 4, 4), blk, 0, stream>>>(
        KBF, WBF + 2097152, XK, ipb + 2048, 1024, 1024, 1024, 1024,
        1048576L, 0, 0, 0, 524288L, 0, 1);
    // 3) PSIG (triangular)
    mfma_nt<128, 128, 1, true><<<dim3(4, 4, 64), blk, 0, stream>>>(
        XQAQ, XK, PSIG, nullptr, 64, 2048, 1024, 512,
        1048576L, 64, 524288L, 64, 4194304L, 262144L, 16);

    // 4) fused: DP (blocks 0-63) + VT proj (blocks 192-319); XK part (64-191)
    //    recomputes XK harmlessly (idempotent, same inputs -> same outputs,
    //    no reader until attn) to keep the grid layout simple.
    dp_kv_k<<<dim3(320), blk, 0, stream>>>(PSIG, ALPHA, KBF, VBF, WBF, ipb, XK, VT);

    // 5) fused attention
    fused_attn_k<<<dim3(64, 32, 1), blk, 0, stream>>>(XQAQ, XK, VT, ALPHA, XO);

    // 6) out = XO @ ow^T + ob  (f32)
    mfma_nt<128, 128, 3><<<dim3(8, 16, 1), blk, 0, stream>>>(
        XO, OWBF, out, ob, 1024, 1024, 1024, 1024, 0, 0, 0, 0, 0, 0, 1);
}

// Round 21
// 161.336 us; speedup vs baseline: 1.6277x; 1.1492x over previous
//
#include <hip/hip_runtime.h>
#include <hip/hip_fp16.h>
#include <hip/hip_bf16.h>
#include <math.h>

typedef unsigned short u16;
typedef __attribute__((ext_vector_type(8))) short bf16x8;
typedef __attribute__((ext_vector_type(8))) unsigned short u16x8;
typedef __attribute__((ext_vector_type(4))) unsigned short u16x4;
typedef __attribute__((ext_vector_type(4))) float f32x4;

static constexpr float CLAMPF = 3.8918202981106265f; // -log(1/0.98 - 1)
static constexpr float SCALEF = 0.125f;              // 1/sqrt(64)
static constexpr float ASCALE = 16384.f;             // 2^14 alpha storage scale

__device__ __forceinline__ u16 f2bf(float x) {
    __hip_bfloat16 h = __float2bfloat16(x);
    return *reinterpret_cast<u16*>(&h);
}

// ---------------------------------------------------------------------------
// Fused f32 -> bf16 conversion (one dispatch). key/val: only tokens < 512 of
// each batch are reachable (triangular alpha), stored COMPACT (4*512,1024).
// Segments (float4 units): q 524288 | key 524288 | val 524288 | W 1048576 |
// ow 262144. Total 2883584 float4s -> 11264 blocks.
// ---------------------------------------------------------------------------
__global__ __launch_bounds__(256)
void cvt_all_k(const float* __restrict__ q, const float* __restrict__ key,
               const float* __restrict__ val, const float* __restrict__ W,
               const float* __restrict__ ow,
               u16* __restrict__ QBF, u16* __restrict__ KBF,
               u16* __restrict__ VBF, u16* __restrict__ WBF,
               u16* __restrict__ OWBF)
{
    long i = (long)blockIdx.x * 256 + threadIdx.x;
    float4 v;
    u16* dst; long off;
    if (i < 524288) {
        dst = QBF; off = i;
        v = ((const float4*)q)[i];
    } else if (i < 1048576) {
        off = i - 524288;                    // compact (b*512+tok) row, 256 f4/row
        long r = off >> 8, c4 = off & 255;
        long b = r >> 9, tok = r & 511;
        dst = KBF;
        v = ((const float4*)key)[(b * 1024 + tok) * 256 + c4];
    } else if (i < 1572864) {
        off = i - 1048576;
        long r = off >> 8, c4 = off & 255;
        long b = r >> 9, tok = r & 511;
        dst = VBF;
        v = ((const float4*)val)[(b * 1024 + tok) * 256 + c4];
    } else if (i < 2621440) {
        dst = WBF; off = i - 1572864;
        v = ((const float4*)W)[off];
    } else if (i < 2883584) {
        dst = OWBF; off = i - 2621440;
        v = ((const float4*)ow)[off];
    } else return;
    u16x4 o; o.x = f2bf(v.x); o.y = f2bf(v.y); o.z = f2bf(v.z); o.w = f2bf(v.w);
    ((u16x4*)dst)[off] = o;
}

// ---------------------------------------------------------------------------
// bf16 MFMA GEMM body (device fn; LDS passed in), NT form:
// C[m][n] = sum_k A[m][k]*B[n][k]  (+ epilogue)
// EPI: 0=bf16(+opt bias), 1=fp16 sigmoid(CLAMP*tanh(x)), 3=f32+bias,
//      4=bf16 V-transpose store VT[((b*16+h)*64+d)*512 + k] + bias
// TRI: phi triangular skip — tiles with k-tile > q-tile are zero-filled.
// ---------------------------------------------------------------------------
template<int TM, int TN, int EPI, bool TRI>
__device__ __forceinline__
void mfma_body(u16* As, u16* Bs, int bx, int by, int bz,
               const u16* __restrict__ Ag, const u16* __restrict__ Bg,
               void* __restrict__ Cg, const float* __restrict__ bias,
               int K, int lda, int ldb, int ldc,
               long sAb, long sAh, long sBb, long sBh, long sCb, long sCh,
               int hdiv)
{
    int b = bz / hdiv, h = bz % hdiv;
    const u16* A = Ag + (long)b * sAb + (long)h * sAh;
    const u16* B = Bg + (long)b * sBb + (long)h * sBh;

    int tid = threadIdx.x;
    int bm = by * TM, bn = bx * TN;

    constexpr int AC = TM / 32;
    constexpr int BC = TN / 32;
    int srow = tid >> 3;          // 0..31
    int scol = (tid & 7) * 8;     // 0..56

    int wid = tid >> 6, lane = tid & 63;
    int wr = wid >> 1, wc = wid & 1;
    constexpr int MI = TM / 32;
    constexpr int NI = TN / 32;
    int arow0 = wr * (TM / 2) + (lane & 15);
    int bcol0 = wc * (TN / 2) + (lane & 15);
    int koff = (lane >> 4) * 8;

    if constexpr (TRI) {
        if (bx > by) {   // strictly upper triangle: zero-fill
            __half* C = (__half*)Cg + (long)b * sCb + (long)h * sCh;
            int rb = bm + wr * (TM / 2) + (lane >> 4) * 4;
            int cb = bn + wc * (TN / 2) + (lane & 15);
            __half z16 = __float2half(0.f);
#pragma unroll
            for (int mi = 0; mi < MI; ++mi)
#pragma unroll
                for (int ni = 0; ni < NI; ++ni)
#pragma unroll
                    for (int r = 0; r < 4; ++r)
                        C[(long)(rb + 16 * mi + r) * ldc + cb + 16 * ni] = z16;
            return;
        }
    }

    f32x4 acc[MI][NI];
#pragma unroll
    for (int i = 0; i < MI; ++i)
#pragma unroll
        for (int j = 0; j < NI; ++j) acc[i][j] = (f32x4){0.f, 0.f, 0.f, 0.f};

    for (int kt = 0; kt < K; kt += 64) {
        u16x8 av[AC], bv[BC];
#pragma unroll
        for (int c = 0; c < AC; ++c)
            av[c] = *(const u16x8*)(A + (long)(bm + srow + 32 * c) * lda + kt + scol);
#pragma unroll
        for (int c = 0; c < BC; ++c)
            bv[c] = *(const u16x8*)(B + (long)(bn + srow + 32 * c) * ldb + kt + scol);
        __syncthreads();
#pragma unroll
        for (int c = 0; c < AC; ++c)
            *(u16x8*)&As[(srow + 32 * c) * 64 + scol] = av[c];
#pragma unroll
        for (int c = 0; c < BC; ++c)
            *(u16x8*)&Bs[(srow + 32 * c) * 64 + scol] = bv[c];
        __syncthreads();

#pragma unroll
        for (int ks = 0; ks < 2; ++ks) {
            bf16x8 af[MI], bfr[NI];
#pragma unroll
            for (int mi = 0; mi < MI; ++mi)
                af[mi] = *(const bf16x8*)&As[(arow0 + 16 * mi) * 64 + ks * 32 + koff];
#pragma unroll
            for (int ni = 0; ni < NI; ++ni)
                bfr[ni] = *(const bf16x8*)&Bs[(bcol0 + 16 * ni) * 64 + ks * 32 + koff];
#pragma unroll
            for (int mi = 0; mi < MI; ++mi)
#pragma unroll
                for (int ni = 0; ni < NI; ++ni)
                    acc[mi][ni] = __builtin_amdgcn_mfma_f32_16x16x32_bf16(
                        af[mi], bfr[ni], acc[mi][ni], 0, 0, 0);
        }
    }

    // Epilogue
    int rbase = bm + wr * (TM / 2) + (lane >> 4) * 4;
    int cbase = bn + wc * (TN / 2) + (lane & 15);
#pragma unroll
    for (int mi = 0; mi < MI; ++mi) {
#pragma unroll
        for (int ni = 0; ni < NI; ++ni) {
            int m0 = rbase + 16 * mi;
            int n = cbase + 16 * ni;
            if constexpr (EPI == 0) {
                u16* C = (u16*)Cg + (long)b * sCb + (long)h * sCh;
                float bvv = bias ? bias[n] : 0.f;
#pragma unroll
                for (int r = 0; r < 4; ++r)
                    C[(long)(m0 + r) * ldc + n] = f2bf(acc[mi][ni][r] + bvv);
            } else if constexpr (EPI == 1) {
                __half* C = (__half*)Cg + (long)b * sCb + (long)h * sCh;
#pragma unroll
                for (int r = 0; r < 4; ++r) {
                    float x = acc[mi][ni][r];
                    float e2 = __expf(2.f * x);
                    float tv = CLAMPF - (2.f * CLAMPF) * __builtin_amdgcn_rcpf(e2 + 1.f);
                    float pv = __builtin_amdgcn_rcpf(1.f + __expf(-tv));
                    C[(long)(m0 + r) * ldc + n] = __float2half(pv);
                }
            } else if constexpr (EPI == 3) {
                float* C = (float*)Cg + (long)b * sCb + (long)h * sCh;
                float bvv = bias[n];
#pragma unroll
                for (int r = 0; r < 4; ++r)
                    C[(long)(m0 + r) * ldc + n] = acc[mi][ni][r] + bvv;
            } else { // EPI == 4: VT[((b*16 + n/64)*64 + n%64)*512 + k], k = m0+r
                u16* C = (u16*)Cg;
                float bvv = bias[n];
                long vaddr = ((long)(b * 16 + (n >> 6)) * 64 + (n & 63)) * 512 + m0;
                u16x4 pk;
                pk.x = f2bf(acc[mi][ni][0] + bvv);
                pk.y = f2bf(acc[mi][ni][1] + bvv);
                pk.z = f2bf(acc[mi][ni][2] + bvv);
                pk.w = f2bf(acc[mi][ni][3] + bvv);
                *(u16x4*)(C + vaddr) = pk;
            }
        }
    }
}

template<int TM, int TN, int EPI, bool TRI = false>
__global__ __launch_bounds__(256)
void mfma_nt(const u16* __restrict__ Ag, const u16* __restrict__ Bg,
             void* __restrict__ Cg, const float* __restrict__ bias,
             int K, int lda, int ldb, int ldc,
             long sAb, long sAh, long sBb, long sBh, long sCb, long sCh,
             int hdiv)
{
    __shared__ u16 As[TM * 64];
    __shared__ u16 Bs[TN * 64];
    mfma_body<TM, TN, EPI, TRI>(As, Bs, blockIdx.x, blockIdx.y, blockIdx.z,
                                Ag, Bg, Cg, bias, K, lda, ldb, ldc,
                                sAb, sAh, sBb, sBh, sCb, sCh, hdiv);
}

// ---------------------------------------------------------------------------
// Merged XQAQ + XK projections (independent; run concurrently).
// Blocks 0-255: XQAQ tiles (16x16). Blocks 256-383: XK tiles (8,4,4).
// KBF is COMPACT (4*512,1024): per-batch stride 512 rows.
// ---------------------------------------------------------------------------
__global__ __launch_bounds__(256)
void proj_qk_k(const u16* __restrict__ QBF, const u16* __restrict__ KBF,
               const u16* __restrict__ WBF, const float* __restrict__ ipb,
               u16* __restrict__ XQAQ, u16* __restrict__ XK)
{
    __shared__ u16 As[128 * 64];
    __shared__ u16 Bs[128 * 64];
    int bid = blockIdx.x;
    if (bid < 256) {
        mfma_body<128, 128, 0, false>(As, Bs, bid & 15, bid >> 4, 0,
            QBF, WBF, XQAQ, ipb, 1024, 1024, 1024, 2048, 0, 0, 0, 0, 0, 0, 1);
    } else {
        int idx = bid - 256;
        mfma_body<128, 128, 0, false>(As, Bs, idx & 7, (idx >> 3) & 3, idx >> 5,
            KBF, WBF + 2097152, XK, ipb + 2048, 1024, 1024, 1024, 1024,
            524288L, 0, 0, 0, 524288L, 0, 1);
    }
}

// ---------------------------------------------------------------------------
// Monotonic DP (r11/r15 best body) FUSED with the VT projection:
// grid 192 x 256 thr. Blocks 0-63: DP slice n=bid (wave 0 only).
// Blocks 64-191: VT tiles — run concurrently on CUs the DP leaves idle.
// VBF is COMPACT (4*512,1024).
// ---------------------------------------------------------------------------
#define DPL8(J) (*(const uint4*)(p + (long)min((J), 510) * 512 + k0))

#define DSTEP(PC, J) do { \
    const __half2* hp = (const __half2*)&(PC); \
    float pv[8]; \
    { float2 q01 = __half22float2(hp[0]); pv[0] = q01.x; pv[1] = q01.y; } \
    { float2 q23 = __half22float2(hp[1]); pv[2] = q23.x; pv[3] = q23.y; } \
    { float2 q45 = __half22float2(hp[2]); pv[4] = q45.x; pv[5] = q45.y; } \
    { float2 q67 = __half22float2(hp[3]); pv[6] = q67.x; pv[7] = q67.y; } \
    float c[8]; \
    _Pragma("unroll") \
    for (int r = 0; r < 8; ++r) c[r] = fmaf(-a[r], pv[r], a[r]); \
    float cp = __shfl_up(c[7], 1, 64); \
    if (lane == 0) cp = 0.f; \
    a[0] = fmaf(a[0], pv[0], cp); \
    _Pragma("unroll") \
    for (int r = 1; r < 8; ++r) a[r] = fmaf(a[r], pv[r], c[r - 1]); \
    uint4 st; \
    { __half2 h0 = __floats2half2_rn(a[0], a[1]), h1 = __floats2half2_rn(a[2], a[3]); \
      st.x = *(unsigned*)&h0; st.y = *(unsigned*)&h1; } \
    { __half2 h2 = __floats2half2_rn(a[4], a[5]), h3 = __floats2half2_rn(a[6], a[7]); \
      st.z = *(unsigned*)&h2; st.w = *(unsigned*)&h3; } \
    *(uint4*)(al + (long)(J) * 512 + k0) = st; \
} while (0)

__global__ __launch_bounds__(256)
void dp_v_k(const __half* __restrict__ P, __half* __restrict__ AL,
            const u16* __restrict__ VBF, const u16* __restrict__ WBF,
            const float* __restrict__ ipb, u16* __restrict__ VT)
{
    __shared__ u16 As[128 * 64];
    __shared__ u16 Bs[128 * 64];
    int bid = blockIdx.x;

    if (bid >= 64) {             // VT projection tiles: (8,4,4) flattened
        int idx = bid - 64;
        mfma_body<128, 128, 4, false>(As, Bs, idx & 7, (idx >> 3) & 3, idx >> 5,
            VBF, WBF + 3145728, VT, ipb + 3072, 1024, 1024, 1024, 0,
            524288L, 0, 0, 0, 0, 0, 1);
        return;
    }

    // ---- DP: blocks 0..63, wave 0 only ----
    if (threadIdx.x >= 64) return;
    int n = bid;
    int lane = threadIdx.x;                 // 0..63
    const __half* p = P + (long)n * 262144; // (512,512) sigmoid probs
    __half* al = AL + (long)n * 262144;     // (512,512) linear alpha (scaled)
    int k0 = lane * 8;

    float a[8];
#pragma unroll
    for (int r = 0; r < 8; ++r) a[r] = 0.f;
    if (lane == 0) a[0] = ASCALE;
    {   // column 0 = init distribution
        uint4 st;
        __half2 h0 = __floats2half2_rn(a[0], a[1]), h1 = __floats2half2_rn(a[2], a[3]);
        __half2 h2 = __floats2half2_rn(a[4], a[5]), h3 = __floats2half2_rn(a[6], a[7]);
        st.x = *(unsigned*)&h0; st.y = *(unsigned*)&h1;
        st.z = *(unsigned*)&h2; st.w = *(unsigned*)&h3;
        *(uint4*)(al + k0) = st;
    }

    int j = 1;
    uint4 f0 = DPL8(0), f1 = DPL8(1), f2 = DPL8(2), f3 = DPL8(3);
    uint4 f4 = DPL8(4), f5 = DPL8(5), f6 = DPL8(6), f7 = DPL8(7);

    while (j + 7 < 512) {
        DSTEP(f0, j); f0 = DPL8(j + 7); ++j;
        DSTEP(f1, j); f1 = DPL8(j + 7); ++j;
        DSTEP(f2, j); f2 = DPL8(j + 7); ++j;
        DSTEP(f3, j); f3 = DPL8(j + 7); ++j;
        DSTEP(f4, j); f4 = DPL8(j + 7); ++j;
        DSTEP(f5, j); f5 = DPL8(j + 7); ++j;
        DSTEP(f6, j); f6 = DPL8(j + 7); ++j;
        DSTEP(f7, j); f7 = DPL8(j + 7); ++j;
    }
    while (j < 512) {
        DSTEP(f0, j);
        f0 = f1; f1 = f2; f2 = f3; f3 = f4; f4 = f5; f5 = f6; f6 = f7;
        ++j;
    }
}

// ---------------------------------------------------------------------------
// Fused attention, k < 512 only (alpha == 0 beyond), 4-way k-split of 128.
// ---------------------------------------------------------------------------
__global__ __launch_bounds__(256, 4)
void fused_attn_k(const u16* __restrict__ XQAQ, const u16* __restrict__ XK,
                  const u16* __restrict__ VT, const __half* __restrict__ AL,
                  u16* __restrict__ XO)
{
    __shared__ u16 wtile[4][2048];
    __shared__ float co[4][16][64];
    __shared__ float cml[4][2][16];

    int n = blockIdx.x; int b = n >> 4, h = n & 15;
    int tid = threadIdx.x, wave = tid >> 6, lane = tid & 63;
    int l15 = lane & 15, l4 = lane >> 4;
    int qg = blockIdx.y * 16;
    u16* wlds = wtile[wave];
    int swz = (l15 & 7) << 3;

    float m = -3.0e38f, lsum = 0.f;
    f32x4 o[4];
#pragma unroll
    for (int df = 0; df < 4; ++df) o[df] = (f32x4){0.f, 0.f, 0.f, 0.f};

    if (wave * 128 < qg + 16) {
        const u16* qbase = XQAQ + (long)(b * 512 + qg + l15) * 2048 + 1024 + h * 64 + l4 * 8;
        bf16x8 qf0 = *(const bf16x8*)(qbase);
        bf16x8 qf1 = *(const bf16x8*)(qbase + 32);

        const u16* kbase = XK + (long)(b * 512 + wave * 128 + l15) * 1024 + h * 64 + l4 * 8;
        const __half* abase = AL + (long)(n * 512 + qg + l15) * 512 + wave * 128 + l4 * 4;
        const u16* vbase = VT + (long)(n * 64 + l15) * 512 + wave * 128 + l4 * 8;

        uint2 areg[8];
#pragma unroll
        for (int kf = 0; kf < 8; ++kf)
            areg[kf] = *(const uint2*)(abase + kf * 16);

        f32x4 s[8];
#pragma unroll
        for (int kf = 0; kf < 8; ++kf) {
            const u16* kb = kbase + (long)(kf * 16) * 1024;
            bf16x8 k0 = *(const bf16x8*)kb;
            bf16x8 k1 = *(const bf16x8*)(kb + 32);
            f32x4 acc = (f32x4){0.f, 0.f, 0.f, 0.f};
            acc = __builtin_amdgcn_mfma_f32_16x16x32_bf16(k0, qf0, acc, 0, 0, 0);
            acc = __builtin_amdgcn_mfma_f32_16x16x32_bf16(k1, qf1, acc, 0, 0, 0);
            s[kf] = acc;
        }

        float mt = -3.0e38f;
#pragma unroll
        for (int kf = 0; kf < 8; ++kf)
            mt = fmaxf(mt, fmaxf(fmaxf(s[kf][0], s[kf][1]), fmaxf(s[kf][2], s[kf][3])));
        mt = fmaxf(mt, __shfl_xor(mt, 16, 64));
        mt = fmaxf(mt, __shfl_xor(mt, 32, 64));
        m = mt;
        float negm = -mt * SCALEF;

#pragma unroll
        for (int kf = 0; kf < 8; ++kf) {
            float2 a01 = __half22float2(*(__half2*)&areg[kf].x);
            float2 a23 = __half22float2(*(__half2*)&areg[kf].y);
            float w0 = a01.x * __expf(fmaf(s[kf][0], SCALEF, negm));
            float w1 = a01.y * __expf(fmaf(s[kf][1], SCALEF, negm));
            float w2 = a23.x * __expf(fmaf(s[kf][2], SCALEF, negm));
            float w3 = a23.y * __expf(fmaf(s[kf][3], SCALEF, negm));
            lsum += (w0 + w1) + (w2 + w3);
            u16x4 wp; wp.x = f2bf(w0); wp.y = f2bf(w1); wp.z = f2bf(w2); wp.w = f2bf(w3);
            *(u16x4*)&wlds[(l15 * 128 + kf * 16 + l4 * 4) ^ swz] = wp;
        }

#pragma unroll
        for (int ks2 = 0; ks2 < 4; ++ks2) {
            bf16x8 wf = *(const bf16x8*)&wlds[(l15 * 128 + ks2 * 32 + l4 * 8) ^ swz];
#pragma unroll
            for (int df = 0; df < 4; ++df) {
                const u16* vb = vbase + (long)(df * 16) * 512 + ks2 * 32;
                bf16x8 vf = *(const bf16x8*)vb;
                o[df] = __builtin_amdgcn_mfma_f32_16x16x32_bf16(wf, vf, o[df], 0, 0, 0);
            }
        }

        lsum += __shfl_xor(lsum, 16, 64);
        lsum += __shfl_xor(lsum, 32, 64);
    }

    if (lane < 16) { cml[wave][0][l15] = m; cml[wave][1][l15] = lsum; }
#pragma unroll
    for (int df = 0; df < 4; ++df)
#pragma unroll
        for (int r = 0; r < 4; ++r)
            co[wave][l4 * 4 + r][df * 16 + l15] = o[df][r];
    __syncthreads();

    int q = tid >> 4, d0 = (tid & 15) * 4;
    float m0 = cml[0][0][q], m1 = cml[1][0][q], m2 = cml[2][0][q], m3 = cml[3][0][q];
    float ms = fmaxf(fmaxf(m0, m1), fmaxf(m2, m3));
    float c0w = __expf((m0 - ms) * SCALEF), c1w = __expf((m1 - ms) * SCALEF);
    float c2w = __expf((m2 - ms) * SCALEF), c3w = __expf((m3 - ms) * SCALEF);
    float lt = c0w * cml[0][1][q] + c1w * cml[1][1][q]
             + c2w * cml[2][1][q] + c3w * cml[3][1][q];
    f32x4 o0 = *(const f32x4*)&co[0][q][d0];
    f32x4 o1 = *(const f32x4*)&co[1][q][d0];
    f32x4 o2 = *(const f32x4*)&co[2][q][d0];
    f32x4 o3 = *(const f32x4*)&co[3][q][d0];
    float inv = __builtin_amdgcn_rcpf(lt);
    u16x4 st;
#pragma unroll
    for (int j = 0; j < 4; ++j)
        st[j] = f2bf((c0w * o0[j] + c1w * o1[j] + c2w * o2[j] + c3w * o3[j]) * inv);
    *(u16x4*)&XO[(long)(b * 512 + qg + q) * 1024 + h * 64 + d0] = st;
}

// ---------------------------------------------------------------------------
extern "C" void kernel_launch(void* const* d_in, const int* in_sizes, int n_in,
                              void* d_out, int out_size, void* d_ws, size_t ws_size,
                              hipStream_t stream)
{
    const float* q   = (const float*)d_in[0];
    const float* key = (const float*)d_in[1];
    const float* val = (const float*)d_in[2];
    const float* W   = (const float*)d_in[3];
    const float* ipb = (const float*)d_in[4];
    const float* ow  = (const float*)d_in[5];
    const float* ob  = (const float*)d_in[6];
    float* out = (float*)d_out;
    char* w = (char*)d_ws;

    // Workspace layout (bytes). Total 107,479,040 B (~102.5 MiB).
    // KBF/VBF/WBF persist past the PSIG write, so they live OUTSIDE the
    // PSIG/ALPHA regions; only QBF overlays PSIG (consumed before PSIG).
    __half* PSIG  = (__half*)(w);                 // 32 MiB (64,512,512) fp16
    __half* ALPHA = (__half*)(w + 33554432);      // 32 MiB (64,512,512) fp16
    u16*    XQAQ  = (u16*)(w + 67108864);         // 8 MiB  (2048,2048) bf16
    u16*    XK    = (u16*)(w + 75497472);         // 4 MiB  (4*512,1024) bf16
    u16*    VT    = (u16*)(w + 79691776);         // 4 MiB  (64,64,512) bf16
    u16*    XO    = (u16*)(w + 83886080);         // 4 MiB  (2048,1024) bf16
    u16*    OWBF  = (u16*)(w + 88080384);         // 2 MiB  (1024,1024) bf16
    u16*    KBF   = (u16*)(w + 90177536);         // 4 MiB  (4*512,1024) compact
    u16*    VBF   = (u16*)(w + 94371840);         // 4 MiB  (4*512,1024) compact
    u16*    WBF   = (u16*)(w + 98566144);         // 8 MiB  (4096,1024) bf16
    u16*    QBF   = (u16*)(w);                    // 4 MiB overlay in PSIG

    dim3 blk(256);

    // 0) f32 -> bf16 copies (key/val trimmed to tokens < 512, compact)
    cvt_all_k<<<dim3(11264), blk, 0, stream>>>(
        q, key, val, W, ow, QBF, KBF, VBF, WBF, OWBF);

    // 1) merged XQAQ + XK projections (independent, concurrent)
    proj_qk_k<<<dim3(384), blk, 0, stream>>>(QBF, KBF, WBF, ipb, XQAQ, XK);

    // 2) PSIG[n][q][k<512] = sigmoid(CLAMP*tanh(xqa . xk)); triangular
    mfma_nt<128, 128, 1, true><<<dim3(4, 4, 64), blk, 0, stream>>>(
        XQAQ, XK, PSIG, nullptr, 64, 2048, 1024, 512,
        1048576L, 64, 524288L, 64, 4194304L, 262144L, 16);

    // 3) fused: DP (blocks 0-63) + VT projection (blocks 64-191)
    dp_v_k<<<dim3(192), blk, 0, stream>>>(PSIG, ALPHA, VBF, WBF, ipb, VT);

    // 4) fused attention
    fused_attn_k<<<dim3(64, 32, 1), blk, 0, stream>>>(XQAQ, XK, VT, ALPHA, XO);

    // 5) out = XO @ ow^T + ob  (f32)
    mfma_nt<128, 128, 3><<<dim3(8, 16, 1), blk, 0, stream>>>(
        XO, OWBF, out, ob, 1024, 1024, 1024, 1024, 0, 0, 0, 0, 0, 0, 1);
}

// Round 22
// 160.935 us; speedup vs baseline: 1.6318x; 1.0025x over previous
//
#include <hip/hip_runtime.h>
#include <hip/hip_fp16.h>
#include <hip/hip_bf16.h>
#include <math.h>

typedef unsigned short u16;
typedef __attribute__((ext_vector_type(8))) short bf16x8;
typedef __attribute__((ext_vector_type(8))) unsigned short u16x8;
typedef __attribute__((ext_vector_type(4))) unsigned short u16x4;
typedef __attribute__((ext_vector_type(4))) float f32x4;

static constexpr float CLAMPF = 3.8918202981106265f; // -log(1/0.98 - 1)
static constexpr float SCALEF = 0.125f;              // 1/sqrt(64)
static constexpr float ASCALE = 16384.f;             // 2^14 alpha storage scale

__device__ __forceinline__ u16 f2bf(float x) {
    __hip_bfloat16 h = __float2bfloat16(x);
    return *reinterpret_cast<u16*>(&h);
}

// ---------------------------------------------------------------------------
// Fused f32 -> bf16 conversion (one dispatch). key/val: only tokens < 512 of
// each batch are reachable (triangular alpha), stored COMPACT (4*512,1024).
// ---------------------------------------------------------------------------
__global__ __launch_bounds__(256)
void cvt_all_k(const float* __restrict__ q, const float* __restrict__ key,
               const float* __restrict__ val, const float* __restrict__ W,
               const float* __restrict__ ow,
               u16* __restrict__ QBF, u16* __restrict__ KBF,
               u16* __restrict__ VBF, u16* __restrict__ WBF,
               u16* __restrict__ OWBF)
{
    long i = (long)blockIdx.x * 256 + threadIdx.x;
    float4 v;
    u16* dst; long off;
    if (i < 524288) {
        dst = QBF; off = i;
        v = ((const float4*)q)[i];
    } else if (i < 1048576) {
        off = i - 524288;                    // compact (b*512+tok) row, 256 f4/row
        long r = off >> 8, c4 = off & 255;
        long b = r >> 9, tok = r & 511;
        dst = KBF;
        v = ((const float4*)key)[(b * 1024 + tok) * 256 + c4];
    } else if (i < 1572864) {
        off = i - 1048576;
        long r = off >> 8, c4 = off & 255;
        long b = r >> 9, tok = r & 511;
        dst = VBF;
        v = ((const float4*)val)[(b * 1024 + tok) * 256 + c4];
    } else if (i < 2621440) {
        dst = WBF; off = i - 1572864;
        v = ((const float4*)W)[off];
    } else if (i < 2883584) {
        dst = OWBF; off = i - 2621440;
        v = ((const float4*)ow)[off];
    } else return;
    u16x4 o; o.x = f2bf(v.x); o.y = f2bf(v.y); o.z = f2bf(v.z); o.w = f2bf(v.w);
    ((u16x4*)dst)[off] = o;
}

// ---------------------------------------------------------------------------
// bf16 MFMA GEMM body (device fn; LDS passed in), NT form:
// C[m][n] = sum_k A[m][k]*B[n][k]  (+ epilogue)
// EPI: 0=bf16(+opt bias), 1=fp16 sigmoid(CLAMP*tanh(x)), 3=f32+bias,
//      4=bf16 V-transpose store VT[((b*16+h)*64+d)*512 + k] + bias
// TRI: phi triangular skip — tiles with k-tile > q-tile are zero-filled.
// ---------------------------------------------------------------------------
template<int TM, int TN, int EPI, bool TRI>
__device__ __forceinline__
void mfma_body(u16* As, u16* Bs, int bx, int by, int bz,
               const u16* __restrict__ Ag, const u16* __restrict__ Bg,
               void* __restrict__ Cg, const float* __restrict__ bias,
               int K, int lda, int ldb, int ldc,
               long sAb, long sAh, long sBb, long sBh, long sCb, long sCh,
               int hdiv)
{
    int b = bz / hdiv, h = bz % hdiv;
    const u16* A = Ag + (long)b * sAb + (long)h * sAh;
    const u16* B = Bg + (long)b * sBb + (long)h * sBh;

    int tid = threadIdx.x;
    int bm = by * TM, bn = bx * TN;

    constexpr int AC = TM / 32;
    constexpr int BC = TN / 32;
    int srow = tid >> 3;          // 0..31
    int scol = (tid & 7) * 8;     // 0..56

    int wid = tid >> 6, lane = tid & 63;
    int wr = wid >> 1, wc = wid & 1;
    constexpr int MI = TM / 32;
    constexpr int NI = TN / 32;
    int arow0 = wr * (TM / 2) + (lane & 15);
    int bcol0 = wc * (TN / 2) + (lane & 15);
    int koff = (lane >> 4) * 8;

    if constexpr (TRI) {
        if (bx > by) {   // strictly upper triangle: zero-fill
            __half* C = (__half*)Cg + (long)b * sCb + (long)h * sCh;
            int rb = bm + wr * (TM / 2) + (lane >> 4) * 4;
            int cb = bn + wc * (TN / 2) + (lane & 15);
            __half z16 = __float2half(0.f);
#pragma unroll
            for (int mi = 0; mi < MI; ++mi)
#pragma unroll
                for (int ni = 0; ni < NI; ++ni)
#pragma unroll
                    for (int r = 0; r < 4; ++r)
                        C[(long)(rb + 16 * mi + r) * ldc + cb + 16 * ni] = z16;
            return;
        }
    }

    f32x4 acc[MI][NI];
#pragma unroll
    for (int i = 0; i < MI; ++i)
#pragma unroll
        for (int j = 0; j < NI; ++j) acc[i][j] = (f32x4){0.f, 0.f, 0.f, 0.f};

    for (int kt = 0; kt < K; kt += 64) {
        u16x8 av[AC], bv[BC];
#pragma unroll
        for (int c = 0; c < AC; ++c)
            av[c] = *(const u16x8*)(A + (long)(bm + srow + 32 * c) * lda + kt + scol);
#pragma unroll
        for (int c = 0; c < BC; ++c)
            bv[c] = *(const u16x8*)(B + (long)(bn + srow + 32 * c) * ldb + kt + scol);
        __syncthreads();
#pragma unroll
        for (int c = 0; c < AC; ++c)
            *(u16x8*)&As[(srow + 32 * c) * 64 + scol] = av[c];
#pragma unroll
        for (int c = 0; c < BC; ++c)
            *(u16x8*)&Bs[(srow + 32 * c) * 64 + scol] = bv[c];
        __syncthreads();

#pragma unroll
        for (int ks = 0; ks < 2; ++ks) {
            bf16x8 af[MI], bfr[NI];
#pragma unroll
            for (int mi = 0; mi < MI; ++mi)
                af[mi] = *(const bf16x8*)&As[(arow0 + 16 * mi) * 64 + ks * 32 + koff];
#pragma unroll
            for (int ni = 0; ni < NI; ++ni)
                bfr[ni] = *(const bf16x8*)&Bs[(bcol0 + 16 * ni) * 64 + ks * 32 + koff];
#pragma unroll
            for (int mi = 0; mi < MI; ++mi)
#pragma unroll
                for (int ni = 0; ni < NI; ++ni)
                    acc[mi][ni] = __builtin_amdgcn_mfma_f32_16x16x32_bf16(
                        af[mi], bfr[ni], acc[mi][ni], 0, 0, 0);
        }
    }

    // Epilogue
    int rbase = bm + wr * (TM / 2) + (lane >> 4) * 4;
    int cbase = bn + wc * (TN / 2) + (lane & 15);
#pragma unroll
    for (int mi = 0; mi < MI; ++mi) {
#pragma unroll
        for (int ni = 0; ni < NI; ++ni) {
            int m0 = rbase + 16 * mi;
            int n = cbase + 16 * ni;
            if constexpr (EPI == 0) {
                u16* C = (u16*)Cg + (long)b * sCb + (long)h * sCh;
                float bvv = bias ? bias[n] : 0.f;
#pragma unroll
                for (int r = 0; r < 4; ++r)
                    C[(long)(m0 + r) * ldc + n] = f2bf(acc[mi][ni][r] + bvv);
            } else if constexpr (EPI == 1) {
                __half* C = (__half*)Cg + (long)b * sCb + (long)h * sCh;
#pragma unroll
                for (int r = 0; r < 4; ++r) {
                    float x = acc[mi][ni][r];
                    float e2 = __expf(2.f * x);
                    float tv = CLAMPF - (2.f * CLAMPF) * __builtin_amdgcn_rcpf(e2 + 1.f);
                    float pv = __builtin_amdgcn_rcpf(1.f + __expf(-tv));
                    C[(long)(m0 + r) * ldc + n] = __float2half(pv);
                }
            } else if constexpr (EPI == 3) {
                float* C = (float*)Cg + (long)b * sCb + (long)h * sCh;
                float bvv = bias[n];
#pragma unroll
                for (int r = 0; r < 4; ++r)
                    C[(long)(m0 + r) * ldc + n] = acc[mi][ni][r] + bvv;
            } else { // EPI == 4: VT[((b*16 + n/64)*64 + n%64)*512 + k], k = m0+r
                u16* C = (u16*)Cg;
                float bvv = bias[n];
                long vaddr = ((long)(b * 16 + (n >> 6)) * 64 + (n & 63)) * 512 + m0;
                u16x4 pk;
                pk.x = f2bf(acc[mi][ni][0] + bvv);
                pk.y = f2bf(acc[mi][ni][1] + bvv);
                pk.z = f2bf(acc[mi][ni][2] + bvv);
                pk.w = f2bf(acc[mi][ni][3] + bvv);
                *(u16x4*)(C + vaddr) = pk;
            }
        }
    }
}

template<int TM, int TN, int EPI, bool TRI = false>
__global__ __launch_bounds__(256)
void mfma_nt(const u16* __restrict__ Ag, const u16* __restrict__ Bg,
             void* __restrict__ Cg, const float* __restrict__ bias,
             int K, int lda, int ldb, int ldc,
             long sAb, long sAh, long sBb, long sBh, long sCb, long sCh,
             int hdiv)
{
    __shared__ u16 As[TM * 64];
    __shared__ u16 Bs[TN * 64];
    mfma_body<TM, TN, EPI, TRI>(As, Bs, blockIdx.x, blockIdx.y, blockIdx.z,
                                Ag, Bg, Cg, bias, K, lda, ldb, ldc,
                                sAb, sAh, sBb, sBh, sCb, sCh, hdiv);
}

// ---------------------------------------------------------------------------
// Critical-path projections only: xqa half of XQAQ (cols 0-1023, needed by
// PSIG) + XK. The xq half (cols 1024-2047, needed only by attn) is deferred
// into the DP's shadow. Blocks 0-127: xqa tiles (bx 0-7, by 0-15).
// Blocks 128-255: XK tiles (8,4,4). KBF COMPACT (4*512,1024).
// ---------------------------------------------------------------------------
__global__ __launch_bounds__(256)
void proj_qk_k(const u16* __restrict__ QBF, const u16* __restrict__ KBF,
               const u16* __restrict__ WBF, const float* __restrict__ ipb,
               u16* __restrict__ XQAQ, u16* __restrict__ XK)
{
    __shared__ u16 As[128 * 64];
    __shared__ u16 Bs[128 * 64];
    int bid = blockIdx.x;
    if (bid < 128) {
        mfma_body<128, 128, 0, false>(As, Bs, bid & 7, bid >> 3, 0,
            QBF, WBF, XQAQ, ipb, 1024, 1024, 1024, 2048, 0, 0, 0, 0, 0, 0, 1);
    } else {
        int idx = bid - 128;
        mfma_body<128, 128, 0, false>(As, Bs, idx & 7, (idx >> 3) & 3, idx >> 5,
            KBF, WBF + 2097152, XK, ipb + 2048, 1024, 1024, 1024, 1024,
            524288L, 0, 0, 0, 524288L, 0, 1);
    }
}

// ---------------------------------------------------------------------------
// Monotonic DP (best-measured body) FUSED with the VT projection AND the
// deferred xq half of XQAQ: grid 320 x 256 thr.
// Blocks 0-63: DP slice n=bid (wave 0 only). Blocks 64-191: VT tiles.
// Blocks 192-319: xq tiles (bx 8-15, by 0-15) writing XQAQ cols 1024-2047.
// All three run concurrently; VT/xq use CUs the latency-bound DP leaves idle.
// ---------------------------------------------------------------------------
#define DPL8(J) (*(const uint4*)(p + (long)min((J), 510) * 512 + k0))

#define DSTEP(PC, J) do { \
    const __half2* hp = (const __half2*)&(PC); \
    float pv[8]; \
    { float2 q01 = __half22float2(hp[0]); pv[0] = q01.x; pv[1] = q01.y; } \
    { float2 q23 = __half22float2(hp[1]); pv[2] = q23.x; pv[3] = q23.y; } \
    { float2 q45 = __half22float2(hp[2]); pv[4] = q45.x; pv[5] = q45.y; } \
    { float2 q67 = __half22float2(hp[3]); pv[6] = q67.x; pv[7] = q67.y; } \
    float c[8]; \
    _Pragma("unroll") \
    for (int r = 0; r < 8; ++r) c[r] = fmaf(-a[r], pv[r], a[r]); \
    float cp = __shfl_up(c[7], 1, 64); \
    if (lane == 0) cp = 0.f; \
    a[0] = fmaf(a[0], pv[0], cp); \
    _Pragma("unroll") \
    for (int r = 1; r < 8; ++r) a[r] = fmaf(a[r], pv[r], c[r - 1]); \
    uint4 st; \
    { __half2 h0 = __floats2half2_rn(a[0], a[1]), h1 = __floats2half2_rn(a[2], a[3]); \
      st.x = *(unsigned*)&h0; st.y = *(unsigned*)&h1; } \
    { __half2 h2 = __floats2half2_rn(a[4], a[5]), h3 = __floats2half2_rn(a[6], a[7]); \
      st.z = *(unsigned*)&h2; st.w = *(unsigned*)&h3; } \
    *(uint4*)(al + (long)(J) * 512 + k0) = st; \
} while (0)

__global__ __launch_bounds__(256)
void dp_v_k(const __half* __restrict__ P, __half* __restrict__ AL,
            const u16* __restrict__ QBF, const u16* __restrict__ VBF,
            const u16* __restrict__ WBF, const float* __restrict__ ipb,
            u16* __restrict__ XQAQ, u16* __restrict__ VT)
{
    __shared__ u16 As[128 * 64];
    __shared__ u16 Bs[128 * 64];
    int bid = blockIdx.x;

    if (bid >= 192) {            // deferred xq half: cols 1024-2047 of XQAQ
        int idx = bid - 192;
        mfma_body<128, 128, 0, false>(As, Bs, 8 + (idx & 7), idx >> 3, 0,
            QBF, WBF, XQAQ, ipb, 1024, 1024, 1024, 2048, 0, 0, 0, 0, 0, 0, 1);
        return;
    }
    if (bid >= 64) {             // VT projection tiles: (8,4,4) flattened
        int idx = bid - 64;
        mfma_body<128, 128, 4, false>(As, Bs, idx & 7, (idx >> 3) & 3, idx >> 5,
            VBF, WBF + 3145728, VT, ipb + 3072, 1024, 1024, 1024, 0,
            524288L, 0, 0, 0, 0, 0, 1);
        return;
    }

    // ---- DP: blocks 0..63, wave 0 only ----
    if (threadIdx.x >= 64) return;
    int n = bid;
    int lane = threadIdx.x;                 // 0..63
    const __half* p = P + (long)n * 262144; // (512,512) sigmoid probs
    __half* al = AL + (long)n * 262144;     // (512,512) linear alpha (scaled)
    int k0 = lane * 8;

    float a[8];
#pragma unroll
    for (int r = 0; r < 8; ++r) a[r] = 0.f;
    if (lane == 0) a[0] = ASCALE;
    {   // column 0 = init distribution
        uint4 st;
        __half2 h0 = __floats2half2_rn(a[0], a[1]), h1 = __floats2half2_rn(a[2], a[3]);
        __half2 h2 = __floats2half2_rn(a[4], a[5]), h3 = __floats2half2_rn(a[6], a[7]);
        st.x = *(unsigned*)&h0; st.y = *(unsigned*)&h1;
        st.z = *(unsigned*)&h2; st.w = *(unsigned*)&h3;
        *(uint4*)(al + k0) = st;
    }

    int j = 1;
    uint4 f0 = DPL8(0), f1 = DPL8(1), f2 = DPL8(2), f3 = DPL8(3);
    uint4 f4 = DPL8(4), f5 = DPL8(5), f6 = DPL8(6), f7 = DPL8(7);

    while (j + 7 < 512) {
        DSTEP(f0, j); f0 = DPL8(j + 7); ++j;
        DSTEP(f1, j); f1 = DPL8(j + 7); ++j;
        DSTEP(f2, j); f2 = DPL8(j + 7); ++j;
        DSTEP(f3, j); f3 = DPL8(j + 7); ++j;
        DSTEP(f4, j); f4 = DPL8(j + 7); ++j;
        DSTEP(f5, j); f5 = DPL8(j + 7); ++j;
        DSTEP(f6, j); f6 = DPL8(j + 7); ++j;
        DSTEP(f7, j); f7 = DPL8(j + 7); ++j;
    }
    while (j < 512) {
        DSTEP(f0, j);
        f0 = f1; f1 = f2; f2 = f3; f3 = f4; f4 = f5; f5 = f6; f6 = f7;
        ++j;
    }
}

// ---------------------------------------------------------------------------
// Fused attention, k < 512 only (alpha == 0 beyond), 4-way k-split of 128.
// ---------------------------------------------------------------------------
__global__ __launch_bounds__(256, 4)
void fused_attn_k(const u16* __restrict__ XQAQ, const u16* __restrict__ XK,
                  const u16* __restrict__ VT, const __half* __restrict__ AL,
                  u16* __restrict__ XO)
{
    __shared__ u16 wtile[4][2048];
    __shared__ float co[4][16][64];
    __shared__ float cml[4][2][16];

    int n = blockIdx.x; int b = n >> 4, h = n & 15;
    int tid = threadIdx.x, wave = tid >> 6, lane = tid & 63;
    int l15 = lane & 15, l4 = lane >> 4;
    int qg = blockIdx.y * 16;
    u16* wlds = wtile[wave];
    int swz = (l15 & 7) << 3;

    float m = -3.0e38f, lsum = 0.f;
    f32x4 o[4];
#pragma unroll
    for (int df = 0; df < 4; ++df) o[df] = (f32x4){0.f, 0.f, 0.f, 0.f};

    if (wave * 128 < qg + 16) {
        const u16* qbase = XQAQ + (long)(b * 512 + qg + l15) * 2048 + 1024 + h * 64 + l4 * 8;
        bf16x8 qf0 = *(const bf16x8*)(qbase);
        bf16x8 qf1 = *(const bf16x8*)(qbase + 32);

        const u16* kbase = XK + (long)(b * 512 + wave * 128 + l15) * 1024 + h * 64 + l4 * 8;
        const __half* abase = AL + (long)(n * 512 + qg + l15) * 512 + wave * 128 + l4 * 4;
        const u16* vbase = VT + (long)(n * 64 + l15) * 512 + wave * 128 + l4 * 8;

        uint2 areg[8];
#pragma unroll
        for (int kf = 0; kf < 8; ++kf)
            areg[kf] = *(const uint2*)(abase + kf * 16);

        f32x4 s[8];
#pragma unroll
        for (int kf = 0; kf < 8; ++kf) {
            const u16* kb = kbase + (long)(kf * 16) * 1024;
            bf16x8 k0 = *(const bf16x8*)kb;
            bf16x8 k1 = *(const bf16x8*)(kb + 32);
            f32x4 acc = (f32x4){0.f, 0.f, 0.f, 0.f};
            acc = __builtin_amdgcn_mfma_f32_16x16x32_bf16(k0, qf0, acc, 0, 0, 0);
            acc = __builtin_amdgcn_mfma_f32_16x16x32_bf16(k1, qf1, acc, 0, 0, 0);
            s[kf] = acc;
        }

        float mt = -3.0e38f;
#pragma unroll
        for (int kf = 0; kf < 8; ++kf)
            mt = fmaxf(mt, fmaxf(fmaxf(s[kf][0], s[kf][1]), fmaxf(s[kf][2], s[kf][3])));
        mt = fmaxf(mt, __shfl_xor(mt, 16, 64));
        mt = fmaxf(mt, __shfl_xor(mt, 32, 64));
        m = mt;
        float negm = -mt * SCALEF;

#pragma unroll
        for (int kf = 0; kf < 8; ++kf) {
            float2 a01 = __half22float2(*(__half2*)&areg[kf].x);
            float2 a23 = __half22float2(*(__half2*)&areg[kf].y);
            float w0 = a01.x * __expf(fmaf(s[kf][0], SCALEF, negm));
            float w1 = a01.y * __expf(fmaf(s[kf][1], SCALEF, negm));
            float w2 = a23.x * __expf(fmaf(s[kf][2], SCALEF, negm));
            float w3 = a23.y * __expf(fmaf(s[kf][3], SCALEF, negm));
            lsum += (w0 + w1) + (w2 + w3);
            u16x4 wp; wp.x = f2bf(w0); wp.y = f2bf(w1); wp.z = f2bf(w2); wp.w = f2bf(w3);
            *(u16x4*)&wlds[(l15 * 128 + kf * 16 + l4 * 4) ^ swz] = wp;
        }

#pragma unroll
        for (int ks2 = 0; ks2 < 4; ++ks2) {
            bf16x8 wf = *(const bf16x8*)&wlds[(l15 * 128 + ks2 * 32 + l4 * 8) ^ swz];
#pragma unroll
            for (int df = 0; df < 4; ++df) {
                const u16* vb = vbase + (long)(df * 16) * 512 + ks2 * 32;
                bf16x8 vf = *(const bf16x8*)vb;
                o[df] = __builtin_amdgcn_mfma_f32_16x16x32_bf16(wf, vf, o[df], 0, 0, 0);
            }
        }

        lsum += __shfl_xor(lsum, 16, 64);
        lsum += __shfl_xor(lsum, 32, 64);
    }

    if (lane < 16) { cml[wave][0][l15] = m; cml[wave][1][l15] = lsum; }
#pragma unroll
    for (int df = 0; df < 4; ++df)
#pragma unroll
        for (int r = 0; r < 4; ++r)
            co[wave][l4 * 4 + r][df * 16 + l15] = o[df][r];
    __syncthreads();

    int q = tid >> 4, d0 = (tid & 15) * 4;
    float m0 = cml[0][0][q], m1 = cml[1][0][q], m2 = cml[2][0][q], m3 = cml[3][0][q];
    float ms = fmaxf(fmaxf(m0, m1), fmaxf(m2, m3));
    float c0w = __expf((m0 - ms) * SCALEF), c1w = __expf((m1 - ms) * SCALEF);
    float c2w = __expf((m2 - ms) * SCALEF), c3w = __expf((m3 - ms) * SCALEF);
    float lt = c0w * cml[0][1][q] + c1w * cml[1][1][q]
             + c2w * cml[2][1][q] + c3w * cml[3][1][q];
    f32x4 o0 = *(const f32x4*)&co[0][q][d0];
    f32x4 o1 = *(const f32x4*)&co[1][q][d0];
    f32x4 o2 = *(const f32x4*)&co[2][q][d0];
    f32x4 o3 = *(const f32x4*)&co[3][q][d0];
    float inv = __builtin_amdgcn_rcpf(lt);
    u16x4 st;
#pragma unroll
    for (int j = 0; j < 4; ++j)
        st[j] = f2bf((c0w * o0[j] + c1w * o1[j] + c2w * o2[j] + c3w * o3[j]) * inv);
    *(u16x4*)&XO[(long)(b * 512 + qg + q) * 1024 + h * 64 + d0] = st;
}

// ---------------------------------------------------------------------------
extern "C" void kernel_launch(void* const* d_in, const int* in_sizes, int n_in,
                              void* d_out, int out_size, void* d_ws, size_t ws_size,
                              hipStream_t stream)
{
    const float* q   = (const float*)d_in[0];
    const float* key = (const float*)d_in[1];
    const float* val = (const float*)d_in[2];
    const float* W   = (const float*)d_in[3];
    const float* ipb = (const float*)d_in[4];
    const float* ow  = (const float*)d_in[5];
    const float* ob  = (const float*)d_in[6];
    float* out = (float*)d_out;
    char* w = (char*)d_ws;

    // Workspace layout (bytes). Total 107,479,040 B (~102.5 MiB).
    // KBF/VBF/WBF persist past the PSIG write -> OUTSIDE PSIG/ALPHA regions.
    // QBF is read by BOTH proj_qk and dp_v (deferred xq half), so it must
    // also persist past PSIG: move it OUT of the PSIG overlay into the XO
    // region? XO is written by attn AFTER dp_v reads QBF... but attn runs
    // after dp_v completes -> safe? XO written at step 4; QBF read at step 3.
    // Sequential stream -> no overlap. Overlay QBF on XO (4 MiB, exact fit).
    __half* PSIG  = (__half*)(w);                 // 32 MiB (64,512,512) fp16
    __half* ALPHA = (__half*)(w + 33554432);      // 32 MiB (64,512,512) fp16
    u16*    XQAQ  = (u16*)(w + 67108864);         // 8 MiB  (2048,2048) bf16
    u16*    XK    = (u16*)(w + 75497472);         // 4 MiB  (4*512,1024) bf16
    u16*    VT    = (u16*)(w + 79691776);         // 4 MiB  (64,64,512) bf16
    u16*    XO    = (u16*)(w + 83886080);         // 4 MiB  (2048,1024) bf16
    u16*    OWBF  = (u16*)(w + 88080384);         // 2 MiB  (1024,1024) bf16
    u16*    KBF   = (u16*)(w + 90177536);         // 4 MiB  (4*512,1024) compact
    u16*    VBF   = (u16*)(w + 94371840);         // 4 MiB  (4*512,1024) compact
    u16*    WBF   = (u16*)(w + 98566144);         // 8 MiB  (4096,1024) bf16
    u16*    QBF   = (u16*)(w + 83886080);         // 4 MiB overlay on XO
                                                   // (QBF dead before attn
                                                   //  writes XO; sequential)

    dim3 blk(256);

    // 0) f32 -> bf16 copies (key/val trimmed to tokens < 512, compact)
    cvt_all_k<<<dim3(11264), blk, 0, stream>>>(
        q, key, val, W, ow, QBF, KBF, VBF, WBF, OWBF);

    // 1) critical-path projections: xqa half + XK (xq half deferred)
    proj_qk_k<<<dim3(256), blk, 0, stream>>>(QBF, KBF, WBF, ipb, XQAQ, XK);

    // 2) PSIG[n][q][k<512] = sigmoid(CLAMP*tanh(xqa . xk)); triangular
    mfma_nt<128, 128, 1, true><<<dim3(4, 4, 64), blk, 0, stream>>>(
        XQAQ, XK, PSIG, nullptr, 64, 2048, 1024, 512,
        1048576L, 64, 524288L, 64, 4194304L, 262144L, 16);

    // 3) fused: DP (0-63) + VT projection (64-191) + deferred xq half (192-319)
    dp_v_k<<<dim3(320), blk, 0, stream>>>(PSIG, ALPHA, QBF, VBF, WBF, ipb, XQAQ, VT);

    // 4) fused attention
    fused_attn_k<<<dim3(64, 32, 1), blk, 0, stream>>>(XQAQ, XK, VT, ALPHA, XO);

    // 5) out = XO @ ow^T + ob  (f32)
    mfma_nt<128, 128, 3><<<dim3(8, 16, 1), blk, 0, stream>>>(
        XO, OWBF, out, ob, 1024, 1024, 1024, 1024, 0, 0, 0, 0, 0, 0, 1);
}